// Round 9
// baseline (1550.258 us; speedup 1.0000x reference)
//
#include <hip/hip_runtime.h>
#include <stdint.h>

#define B_ 16
#define N_ 4096
#define D_ 64
#define S_ 1024
#define K_ 32
#define M_ (B_*S_*K_)   /* 524288 */
#define NQ_ (B_*S_)     /* 16384 */
#define EPS_ 1e-5f
#define WPAD 72         /* bf16 LDS row stride: 72*2=144 B, 16B-aligned frags */

typedef short bf16x8 __attribute__((ext_vector_type(8)));
typedef float f32x4  __attribute__((ext_vector_type(4)));

static __device__ __forceinline__ float bf2f(uint16_t u){
  union{uint32_t i; float f;} v; v.i = ((uint32_t)u) << 16; return v.f;
}
static __device__ __forceinline__ uint16_t f2bf(float f){
  union{uint32_t i; float f;} v; v.f = f;
  uint32_t u = v.i;
  uint32_t r = (u + 0x7FFFu + ((u >> 16) & 1u)) >> 16;   // RNE, finite inputs
  return (uint16_t)r;
}

// One DPP max-combine step on a u64 key. CTRL immediate: 0x111/0x112/0x114/
// 0x118 = row_shr 1/2/4/8, 0x142 = row_bcast15, 0x143 = row_bcast31.
// old = src => lanes with no source keep their value (identity for max).
#define DPP_MAXSTEP(k, CTRL) {                                                   \
  unsigned _lo = (unsigned)(k), _hi = (unsigned)((k) >> 32);                     \
  unsigned _plo = (unsigned)__builtin_amdgcn_update_dpp((int)_lo, (int)_lo,      \
                                                        CTRL, 0xf, 0xf, false); \
  unsigned _phi = (unsigned)__builtin_amdgcn_update_dpp((int)_hi, (int)_hi,      \
                                                        CTRL, 0xf, 0xf, false); \
  unsigned long long _pk = ((unsigned long long)_phi << 32) | _plo;              \
  if(_pk > (k)) (k) = _pk; }

// Build an MFMA A-fragment of h1 = relu(la0*y1 + lb0) in bf16 from y1t[m][c].
// Lane layout (16x16x32 bf16 A): m = lane&15 (+tile), k(c) = (lane>>4)*8 + j.
static __device__ __forceinline__ bf16x8 h1_frag(const uint16_t* __restrict__ y1t,
                                                 const float* la0s, const float* lb0s,
                                                 int m, int kb){
  const uint4 raw = *(const uint4*)(y1t + (size_t)m * 64 + kb);
  uint32_t wrd[4] = {raw.x, raw.y, raw.z, raw.w};
  bf16x8 f;
#pragma unroll
  for(int i = 0; i < 4; ++i){
    int c0 = kb + 2*i;
    float v0 = bf2f((uint16_t)(wrd[i] & 0xFFFFu));
    float v1 = bf2f((uint16_t)(wrd[i] >> 16));
    float h0 = fmaxf(la0s[c0]   * v0 + lb0s[c0],   0.0f);
    float h1 = fmaxf(la0s[c0+1] * v1 + lb0s[c0+1], 0.0f);
    f[2*i]   = (short)f2bf(h0);
    f[2*i+1] = (short)f2bf(h1);
  }
  return f;
}

// ---------------------------------------------------------------------------
// 0) Zero the global stats accumulators (ws is poisoned 0xAA before launch).
// ---------------------------------------------------------------------------
__global__ __launch_bounds__(256) void zero_stats_kernel(float* __restrict__ s){
  s[blockIdx.x * 256 + threadIdx.x] = 0.0f;   // grid 2 -> 512 floats
}

// ---------------------------------------------------------------------------
// 1) FPS: one block/batch, 512 threads (8 waves), 8 pts/thread. Per iter:
//    local argmax -> u64 key (distbits<<32 | ~idx: lowest point idx wins
//    ties = jnp.argmax), DPP wave-max (VALU pipe, ~6x faster than the old
//    ds_swizzle tree), lane63 -> LDS slot, ONE barrier, all threads reduce
//    the 8 slots. Distance math bit-identical to verified rounds 3-8.
// ---------------------------------------------------------------------------
__global__ __launch_bounds__(512) void fps_kernel(const float* __restrict__ xyz,
                                                  float* __restrict__ out_newxyz){
  const int b = blockIdx.x;
  const int tid = threadIdx.x;
  const float* X = xyz + (size_t)b * N_ * 3;
  __shared__ float4 sxyz[N_];                       // 64 KB coord cache
  __shared__ unsigned long long slots[2][8];        // parity double-buffered
  float px[8], py[8], pz[8], dist[8];
#pragma unroll
  for(int t = 0; t < 8; ++t){
    int p = tid + t * 512;
    px[t] = X[p*3 + 0]; py[t] = X[p*3 + 1]; pz[t] = X[p*3 + 2];
    dist[t] = 1e10f;
    sxyz[p] = make_float4(px[t], py[t], pz[t], 0.0f);
  }
  __syncthreads();
  int far = 0;                                      // reference: idx[0] = 0
  for(int it = 0; it < S_; ++it){
    float4 c = sxyz[far];                           // broadcast b128 read
    if(tid == 0){
      float* o = out_newxyz + ((size_t)b * S_ + it) * 3;
      o[0] = c.x; o[1] = c.y; o[2] = c.z;
    }
    if(it == S_ - 1) break;
    float bestd = -1.0f; int bestp = 0;
#pragma unroll
    for(int t = 0; t < 8; ++t){
      float d;
      {
#pragma clang fp contract(off)
        float dx = px[t] - c.x, dy = py[t] - c.y, dz = pz[t] - c.z;
        d = dx*dx + dy*dy + dz*dz;   // match reference: plain mul/add, left-to-right
      }
      float nd = fminf(dist[t], d);
      dist[t] = nd;
      if(nd > bestd){ bestd = nd; bestp = tid + t*512; }  // ascending idx -> first max
    }
    unsigned long long key = ((unsigned long long)__float_as_uint(bestd) << 32)
                           | (unsigned long long)(uint32_t)(~bestp);
    // wave max via DPP: rows 1/2/4/8, then cross-row bcast15/bcast31 -> lane 63
    DPP_MAXSTEP(key, 0x111);
    DPP_MAXSTEP(key, 0x112);
    DPP_MAXSTEP(key, 0x114);
    DPP_MAXSTEP(key, 0x118);
    DPP_MAXSTEP(key, 0x142);
    DPP_MAXSTEP(key, 0x143);
    const int par = it & 1;
    if((tid & 63) == 63) slots[par][tid >> 6] = key;
    __syncthreads();
    const unsigned long long* sp = slots[par];
    unsigned long long bk = sp[0];
#pragma unroll
    for(int w = 1; w < 8; ++w){
      unsigned long long ok = sp[w];
      if(ok > bk) bk = ok;
    }
    far = (int)(~(uint32_t)bk);                     // uniform across block
  }
}

// ---------------------------------------------------------------------------
// 2) Ball query: FP64 sq, bit-identical to numpy float64 ref (verified r3).
// ---------------------------------------------------------------------------
__global__ __launch_bounds__(256) void ballq_kernel(const float* __restrict__ xyz,
                                                    const float* __restrict__ newxyz,
                                                    int* __restrict__ gidx){
  const int wslot = threadIdx.x >> 6;
  const int lane  = threadIdx.x & 63;
  const int q = blockIdx.x * 4 + wslot;
  const int b = q >> 10;
  const float* X = xyz + (size_t)b * N_ * 3;
  const double R2D = 0.2 * 0.2;
  double nx, ny, nz, sa;
  {
    const float* NP = newxyz + (size_t)q * 3;
    nx = (double)NP[0]; ny = (double)NP[1]; nz = (double)NP[2];
    sa = nx*nx + ny*ny + nz*nz;
  }
  __shared__ int sidx[4][K_];
  int count = 0;
  for(int base = 0; base < N_; base += 64){
    int p = base + lane;
    double pxv = (double)X[p*3 + 0], pyv = (double)X[p*3 + 1], pzv = (double)X[p*3 + 2];
    double sb = pxv*pxv + pyv*pyv + pzv*pzv;
    double dt = nx*pxv + ny*pyv + nz*pzv;
    double sq = sa + sb - 2.0 * dt;
    bool inb = !(sq > R2D);
    unsigned long long mask = __ballot(inb);
    int pos = count + __popcll(mask & ((1ull << lane) - 1ull));
    if(inb && pos < K_) sidx[wslot][pos] = p;
    count += (int)__popcll(mask);
    if(count >= K_) break;
  }
  __syncthreads();
  int nvalid = count < K_ ? count : K_;
  if(lane < K_){
    int first = sidx[wslot][0];
    int v = (lane < nvalid) ? sidx[wslot][lane] : first;
    gidx[(size_t)q * K_ + lane] = v;
  }
}

// ---------------------------------------------------------------------------
// 3) Layer 1: gather + concat + GEMM (67->64) + bias. Writes y1 TRANSPOSED
//    y1t[m][c] (row stride 64) for direct 16B MFMA A-frag loads downstream.
//    Fused stats0. Values identical to previous rounds.
// ---------------------------------------------------------------------------
__global__ __launch_bounds__(256)
void layer1_kernel(const float* __restrict__ xyz,
                   const float* __restrict__ pts,
                   const float* __restrict__ newxyz,
                   const int* __restrict__ gidx,
                   const float* __restrict__ w,
                   const float* __restrict__ bias,
                   uint16_t* __restrict__ y1t,
                   float* __restrict__ gstats){
  __shared__ float sm_sum[64*33];
  __shared__ float sm_sq [64*33];
  const int tid = threadIdx.x;
  for(int i = tid; i < 64*33; i += 256){ sm_sum[i] = 0.f; sm_sq[i] = 0.f; }
  __syncthreads();

  const int m = blockIdx.x * 256 + tid;
  const int bs = m >> 5;
  const int b  = bs >> 10;
  const int j  = gidx[m];
  float x[67];
  {
    const float* nxp = newxyz + (size_t)bs * 3;
    const float* pp  = xyz + ((size_t)b * N_ + j) * 3;
    x[0] = pp[0] - nxp[0]; x[1] = pp[1] - nxp[1]; x[2] = pp[2] - nxp[2];
  }
  {
    const float4* pr = (const float4*)(pts + ((size_t)b * N_ + j) * D_);
#pragma unroll
    for(int c4 = 0; c4 < 16; ++c4){
      float4 v = pr[c4];
      x[3 + c4*4 + 0] = v.x; x[3 + c4*4 + 1] = v.y;
      x[3 + c4*4 + 2] = v.z; x[3 + c4*4 + 3] = v.w;
    }
  }
  const int col = tid & 31;
  for(int o = 0; o < 64; ++o){
    float acc = bias[o];
#pragma unroll
    for(int c = 0; c < 67; ++c) acc = fmaf(w[o*67 + c], x[c], acc);
    y1t[(size_t)m * 64 + o] = f2bf(acc);
    atomicAdd(&sm_sum[o*33 + col], acc);
    atomicAdd(&sm_sq [o*33 + col], acc*acc);
  }
  __syncthreads();
  if(tid < 64){
    float s = 0.f;
#pragma unroll
    for(int c = 0; c < 32; ++c) s += sm_sum[tid*33 + c];
    atomicAdd(&gstats[tid], s);
  } else if(tid < 128){
    int o = tid - 64; float s = 0.f;
#pragma unroll
    for(int c = 0; c < 32; ++c) s += sm_sq[o*33 + c];
    atomicAdd(&gstats[64 + o], s);
  }
}

// ---------------------------------------------------------------------------
// 4) Layer 2 stats via MFMA. Wave = 32 m-rows; z2 = mfma(h1,w1b)+b1, stats1
//    accumulated (pre-BN, matching reference). Same mfma order as layer3's
//    recompute => bitwise-identical z2.
// ---------------------------------------------------------------------------
__global__ __launch_bounds__(256)
void layer2_stats_kernel(const uint16_t* __restrict__ y1t,
                         const float* __restrict__ gstats0,
                         const float* __restrict__ g0,
                         const float* __restrict__ bt0,
                         const float* __restrict__ w1,
                         const float* __restrict__ b1,
                         float* __restrict__ gstats1){
  __shared__ short w1b[64*WPAD];
  __shared__ float la0s[64], lb0s[64], b1s[64];
  __shared__ float ssum[64], ssq[64];
  const int tid = threadIdx.x;
#pragma unroll
  for(int i = 0; i < 16; ++i){
    int e = i*256 + tid;                       // 4096 weights
    w1b[(e>>6)*WPAD + (e&63)] = (short)f2bf(w1[e]);
  }
  if(tid < 64){
    float mean = gstats0[tid] * (1.0f / M_);
    float var  = gstats0[64 + tid] * (1.0f / M_) - mean * mean;
    float inv  = 1.0f / sqrtf(var + EPS_);
    float a = g0[tid] * inv;
    la0s[tid] = a; lb0s[tid] = bt0[tid] - mean * a;
    b1s[tid] = b1[tid];
  } else if(tid < 128){
    ssum[tid-64] = 0.f; ssq[tid-64] = 0.f;
  }
  __syncthreads();

  const int wave = tid >> 6, lane = tid & 63;
  const int row = lane & 15, quad = lane >> 4;
  const int wm0 = blockIdx.x * 128 + wave * 32;

  bf16x8 afr[2][2];
#pragma unroll
  for(int s = 0; s < 2; ++s)
#pragma unroll
    for(int k2 = 0; k2 < 2; ++k2)
      afr[s][k2] = h1_frag(y1t, la0s, lb0s, wm0 + s*16 + row, quad*8 + k2*32);

  for(int ot = 0; ot < 4; ++ot){
    bf16x8 bfr0 = *(const bf16x8*)&w1b[(ot*16 + row)*WPAD + quad*8];
    bf16x8 bfr1 = *(const bf16x8*)&w1b[(ot*16 + row)*WPAD + quad*8 + 32];
    const float bb = b1s[ot*16 + row];
    float sum_ = 0.f, sq_ = 0.f;
#pragma unroll
    for(int s = 0; s < 2; ++s){
      f32x4 acc = {0.f, 0.f, 0.f, 0.f};
      acc = __builtin_amdgcn_mfma_f32_16x16x32_bf16(afr[s][0], bfr0, acc, 0, 0, 0);
      acc = __builtin_amdgcn_mfma_f32_16x16x32_bf16(afr[s][1], bfr1, acc, 0, 0, 0);
#pragma unroll
      for(int r = 0; r < 4; ++r){
        float z = acc[r] + bb;
        sum_ += z; sq_ = fmaf(z, z, sq_);
      }
    }
    sum_ += __shfl_xor(sum_, 16, 64); sum_ += __shfl_xor(sum_, 32, 64);
    sq_  += __shfl_xor(sq_,  16, 64); sq_  += __shfl_xor(sq_,  32, 64);
    if(quad == 0){
      atomicAdd(&ssum[ot*16 + row], sum_);
      atomicAdd(&ssq [ot*16 + row], sq_);
    }
  }
  __syncthreads();
  if(tid < 64)       atomicAdd(&gstats1[tid], ssum[tid]);
  else if(tid < 128) atomicAdd(&gstats1[tid], ssq[tid - 64]);
}

// ---------------------------------------------------------------------------
// 5) Layer 3 via MFMA. Recompute z2 (identical mfma order), BN1+ReLU ->
//    h2 bf16 staged per-wave in LDS, L3 GEMM o-tile-at-a-time with immediate
//    epilogue (stats2 + max/min over the wave's 32-m k-group).
// ---------------------------------------------------------------------------
__global__ __launch_bounds__(256)
void layer3_kernel(const uint16_t* __restrict__ y1t,
                   const float* __restrict__ gstats0,
                   const float* __restrict__ g0,
                   const float* __restrict__ bt0,
                   const float* __restrict__ w1,
                   const float* __restrict__ b1,
                   const float* __restrict__ gstats1,
                   const float* __restrict__ g1,
                   const float* __restrict__ bt1,
                   const float* __restrict__ w2,
                   const float* __restrict__ b2,
                   float* __restrict__ gstats2,
                   float* __restrict__ maxk,
                   float* __restrict__ mink){
  __shared__ short w1b[64*WPAD];
  __shared__ short w2b[128*WPAD];
  __shared__ short h2s[4][32*WPAD];
  __shared__ float la0s[64], lb0s[64], la1s[64], lb1s[64], b1s[64], b2s[128];
  __shared__ float ssum[128], ssq[128];
  const int tid = threadIdx.x;
#pragma unroll
  for(int i = 0; i < 16; ++i){
    int e = i*256 + tid;
    w1b[(e>>6)*WPAD + (e&63)] = (short)f2bf(w1[e]);
  }
#pragma unroll
  for(int i = 0; i < 32; ++i){
    int e = i*256 + tid;                       // 8192 weights
    w2b[(e>>6)*WPAD + (e&63)] = (short)f2bf(w2[e]);
  }
  if(tid < 64){
    float mean = gstats0[tid] * (1.0f / M_);
    float var  = gstats0[64 + tid] * (1.0f / M_) - mean * mean;
    float inv  = 1.0f / sqrtf(var + EPS_);
    float a = g0[tid] * inv;
    la0s[tid] = a; lb0s[tid] = bt0[tid] - mean * a;
    b1s[tid] = b1[tid];
  } else if(tid < 128){
    int o = tid - 64;
    float mean = gstats1[o] * (1.0f / M_);
    float var  = gstats1[64 + o] * (1.0f / M_) - mean * mean;
    float inv  = 1.0f / sqrtf(var + EPS_);
    float a = g1[o] * inv;
    la1s[o] = a; lb1s[o] = bt1[o] - mean * a;
  }
  if(tid < 128){ b2s[tid] = b2[tid]; ssum[tid] = 0.f; }
  else         { ssq[tid - 128] = 0.f; }
  __syncthreads();

  const int wave = tid >> 6, lane = tid & 63;
  const int row = lane & 15, quad = lane >> 4;
  const int wm0 = blockIdx.x * 128 + wave * 32;
  short* h2w = &h2s[wave][0];

  // ---- L2 recompute (same order as layer2_stats) + BN1 + ReLU -> h2 LDS
  {
    bf16x8 afr[2][2];
#pragma unroll
    for(int s = 0; s < 2; ++s)
#pragma unroll
      for(int k2 = 0; k2 < 2; ++k2)
        afr[s][k2] = h1_frag(y1t, la0s, lb0s, wm0 + s*16 + row, quad*8 + k2*32);

    for(int ot = 0; ot < 4; ++ot){
      bf16x8 bfr0 = *(const bf16x8*)&w1b[(ot*16 + row)*WPAD + quad*8];
      bf16x8 bfr1 = *(const bf16x8*)&w1b[(ot*16 + row)*WPAD + quad*8 + 32];
      const int o = ot*16 + row;
      const float bb = b1s[o], a1 = la1s[o], c1 = lb1s[o];
#pragma unroll
      for(int s = 0; s < 2; ++s){
        f32x4 acc = {0.f, 0.f, 0.f, 0.f};
        acc = __builtin_amdgcn_mfma_f32_16x16x32_bf16(afr[s][0], bfr0, acc, 0, 0, 0);
        acc = __builtin_amdgcn_mfma_f32_16x16x32_bf16(afr[s][1], bfr1, acc, 0, 0, 0);
#pragma unroll
        for(int r = 0; r < 4; ++r){
          float z = acc[r] + bb;
          float h = fmaxf(a1 * z + c1, 0.0f);
          int ml = s*16 + quad*4 + r;                 // C-layout row
          h2w[ml*WPAD + o] = (short)f2bf(h);          // col = o
        }
      }
    }
  }
  // ---- L3 GEMM: A = h2 (from this wave's LDS region; wave-internal dep)
  {
    bf16x8 hfr[2][2];
#pragma unroll
    for(int s = 0; s < 2; ++s)
#pragma unroll
      for(int k2 = 0; k2 < 2; ++k2)
        hfr[s][k2] = *(const bf16x8*)&h2w[(s*16 + row)*WPAD + quad*8 + k2*32];

    for(int ot = 0; ot < 8; ++ot){
      bf16x8 bfr0 = *(const bf16x8*)&w2b[(ot*16 + row)*WPAD + quad*8];
      bf16x8 bfr1 = *(const bf16x8*)&w2b[(ot*16 + row)*WPAD + quad*8 + 32];
      const int o = ot*16 + row;
      const float bb = b2s[o];
      float sum_ = 0.f, sq_ = 0.f, mx = -1e30f, mn = 1e30f;
#pragma unroll
      for(int s = 0; s < 2; ++s){
        f32x4 acc = {0.f, 0.f, 0.f, 0.f};
        acc = __builtin_amdgcn_mfma_f32_16x16x32_bf16(hfr[s][0], bfr0, acc, 0, 0, 0);
        acc = __builtin_amdgcn_mfma_f32_16x16x32_bf16(hfr[s][1], bfr1, acc, 0, 0, 0);
#pragma unroll
        for(int r = 0; r < 4; ++r){
          float z = acc[r] + bb;
          sum_ += z; sq_ = fmaf(z, z, sq_);
          mx = fmaxf(mx, z); mn = fminf(mn, z);
        }
      }
      sum_ += __shfl_xor(sum_, 16, 64); sum_ += __shfl_xor(sum_, 32, 64);
      sq_  += __shfl_xor(sq_,  16, 64); sq_  += __shfl_xor(sq_,  32, 64);
      mx = fmaxf(mx, __shfl_xor(mx, 16, 64)); mx = fmaxf(mx, __shfl_xor(mx, 32, 64));
      mn = fminf(mn, __shfl_xor(mn, 16, 64)); mn = fminf(mn, __shfl_xor(mn, 32, 64));
      if(quad == 0){
        atomicAdd(&ssum[o], sum_);
        atomicAdd(&ssq [o], sq_);
        maxk[(size_t)(wm0 >> 5) * 128 + o] = mx;     // wave's 32 m == one k-group
        mink[(size_t)(wm0 >> 5) * 128 + o] = mn;
      }
    }
  }
  __syncthreads();
  if(tid < 128) atomicAdd(&gstats2[tid], ssum[tid]);
  else          atomicAdd(&gstats2[tid], ssq[tid - 128]);
}

// ---------------------------------------------------------------------------
// 6) Final: BN2+ReLU on max/min endpoints. Unchanged.
// ---------------------------------------------------------------------------
__global__ __launch_bounds__(256) void final_kernel(const float* __restrict__ maxk,
                                                    const float* __restrict__ mink,
                                                    const float* __restrict__ gstats2,
                                                    const float* __restrict__ g,
                                                    const float* __restrict__ bt,
                                                    float* __restrict__ out_np){
  const int gid = blockIdx.x * 256 + threadIdx.x;
  const int o = gid & 127;
  float mean = gstats2[o] * (1.0f / M_);
  float var  = gstats2[128 + o] * (1.0f / M_) - mean * mean;
  float inv  = 1.0f / sqrtf(var + EPS_);
  float a = g[o] * inv;
  float b = bt[o] - mean * a;
  float mx = maxk[gid], mn = mink[gid];
  out_np[gid] = fmaxf(fmaxf(a * mx + b, 0.0f), fmaxf(a * mn + b, 0.0f));
}

// ---------------------------------------------------------------------------
extern "C" void kernel_launch(void* const* d_in, const int* in_sizes, int n_in,
                              void* d_out, int out_size, void* d_ws, size_t ws_size,
                              hipStream_t stream){
  (void)in_sizes; (void)n_in; (void)out_size;
  const float* xyz = (const float*)d_in[0];
  const float* pts = (const float*)d_in[1];
  const float* w0 = (const float*)d_in[2];  const float* b0  = (const float*)d_in[3];
  const float* g0 = (const float*)d_in[4];  const float* bt0 = (const float*)d_in[5];
  const float* w1 = (const float*)d_in[6];  const float* b1  = (const float*)d_in[7];
  const float* g1 = (const float*)d_in[8];  const float* bt1 = (const float*)d_in[9];
  const float* w2 = (const float*)d_in[10]; const float* b2  = (const float*)d_in[11];
  const float* g2 = (const float*)d_in[12]; const float* bt2 = (const float*)d_in[13];

  float* out    = (float*)d_out;
  float* newxyz = out;                       // (B,S,3)
  float* newpts = out + (size_t)B_ * S_ * 3; // (B,S,128)

  const size_t off_gidx  = 0;
  const size_t off_stats = off_gidx  + (size_t)M_ * 4;
  const size_t off_maxk  = off_stats + 65536;
  const size_t off_mink  = off_maxk  + (size_t)NQ_ * 128 * 4;
  const size_t off_y1    = off_mink  + (size_t)NQ_ * 128 * 4;
  const size_t need      = off_y1    + (size_t)M_ * 64 * 2;
  if(ws_size < need) return;

  char* ws = (char*)d_ws;
  int*      gidx   = (int*)     (ws + off_gidx);
  float*    gstats = (float*)   (ws + off_stats);
  float*    maxk   = (float*)   (ws + off_maxk);
  float*    mink   = (float*)   (ws + off_mink);
  uint16_t* y1t    = (uint16_t*)(ws + off_y1);

  zero_stats_kernel<<<2, 256, 0, stream>>>(gstats);
  fps_kernel  <<<B_, 512, 0, stream>>>(xyz, newxyz);
  ballq_kernel<<<NQ_ / 4, 256, 0, stream>>>(xyz, newxyz, gidx);

  layer1_kernel      <<<M_ / 256, 256, 0, stream>>>(xyz, pts, newxyz, gidx, w0, b0, y1t, gstats);
  layer2_stats_kernel<<<M_ / 128, 256, 0, stream>>>(y1t, gstats, g0, bt0, w1, b1, gstats + 128);
  layer3_kernel      <<<M_ / 128, 256, 0, stream>>>(y1t, gstats, g0, bt0, w1, b1,
                                                    gstats + 128, g1, bt1, w2, b2,
                                                    gstats + 256, maxk, mink);
  final_kernel<<<(NQ_ * 128) / 256, 256, 0, stream>>>(maxk, mink, gstats + 256, g2, bt2, newpts);
}

// Round 10
// 1335.820 us; speedup vs baseline: 1.1605x; 1.1605x over previous
//
#include <hip/hip_runtime.h>
#include <stdint.h>

#define B_ 16
#define N_ 4096
#define D_ 64
#define S_ 1024
#define K_ 32
#define M_ (B_*S_*K_)   /* 524288 */
#define NQ_ (B_*S_)     /* 16384 */
#define EPS_ 1e-5f
#define WPAD 72         /* bf16 LDS row stride: 72*2=144 B, 16B-aligned frags */

typedef short bf16x8 __attribute__((ext_vector_type(8)));
typedef float f32x4  __attribute__((ext_vector_type(4)));

static __device__ __forceinline__ float bf2f(uint16_t u){
  union{uint32_t i; float f;} v; v.i = ((uint32_t)u) << 16; return v.f;
}
static __device__ __forceinline__ uint16_t f2bf(float f){
  union{uint32_t i; float f;} v; v.f = f;
  uint32_t u = v.i;
  uint32_t r = (u + 0x7FFFu + ((u >> 16) & 1u)) >> 16;   // RNE, finite inputs
  return (uint16_t)r;
}

// One DPP max-combine step on a u64 key (verified bit-exact in round 9).
// 0x111/0x112/0x114/0x118 = row_shr 1/2/4/8, 0x142/0x143 = row_bcast15/31.
#define DPP_MAXSTEP(k, CTRL) {                                                   \
  unsigned _lo = (unsigned)(k), _hi = (unsigned)((k) >> 32);                     \
  unsigned _plo = (unsigned)__builtin_amdgcn_update_dpp((int)_lo, (int)_lo,      \
                                                        CTRL, 0xf, 0xf, false); \
  unsigned _phi = (unsigned)__builtin_amdgcn_update_dpp((int)_hi, (int)_hi,      \
                                                        CTRL, 0xf, 0xf, false); \
  unsigned long long _pk = ((unsigned long long)_phi << 32) | _plo;              \
  if(_pk > (k)) (k) = _pk; }

// Build an MFMA A-fragment of h1 = relu(la0*y1 + lb0) in bf16 from y1t[m][c].
static __device__ __forceinline__ bf16x8 h1_frag(const uint16_t* __restrict__ y1t,
                                                 const float* la0s, const float* lb0s,
                                                 int m, int kb){
  const uint4 raw = *(const uint4*)(y1t + (size_t)m * 64 + kb);
  uint32_t wrd[4] = {raw.x, raw.y, raw.z, raw.w};
  bf16x8 f;
#pragma unroll
  for(int i = 0; i < 4; ++i){
    int c0 = kb + 2*i;
    float v0 = bf2f((uint16_t)(wrd[i] & 0xFFFFu));
    float v1 = bf2f((uint16_t)(wrd[i] >> 16));
    float h0 = fmaxf(la0s[c0]   * v0 + lb0s[c0],   0.0f);
    float h1 = fmaxf(la0s[c0+1] * v1 + lb0s[c0+1], 0.0f);
    f[2*i]   = (short)f2bf(h0);
    f[2*i+1] = (short)f2bf(h1);
  }
  return f;
}

// ---------------------------------------------------------------------------
// 0) Zero the global stats accumulators.
// ---------------------------------------------------------------------------
__global__ __launch_bounds__(256) void zero_stats_kernel(float* __restrict__ s){
  s[blockIdx.x * 256 + threadIdx.x] = 0.0f;   // grid 2 -> 512 floats
}

// ---------------------------------------------------------------------------
// 1) FPS: one block/batch, 256 threads (4 waves = 1/SIMD), 16 pts/thread.
//    Round-9 lesson: wave count doesn't change the per-SIMD update cost;
//    it only inflates barrier + slot-reduce. So: 4 waves + DPP reduce
//    (r9-verified) + bestt inline-const tracking (saves 16 v_adds/iter).
//    Distance math bit-identical to verified rounds 3-9.
// ---------------------------------------------------------------------------
__global__ __launch_bounds__(256) void fps_kernel(const float* __restrict__ xyz,
                                                  float* __restrict__ out_newxyz){
  const int b = blockIdx.x;
  const int tid = threadIdx.x;
  const float* X = xyz + (size_t)b * N_ * 3;
  __shared__ float4 sxyz[N_];                       // 64 KB coord cache
  __shared__ unsigned long long slots[2][4];        // parity double-buffered
  float px[16], py[16], pz[16], dist[16];
#pragma unroll
  for(int t = 0; t < 16; ++t){
    int p = tid + t * 256;
    px[t] = X[p*3 + 0]; py[t] = X[p*3 + 1]; pz[t] = X[p*3 + 2];
    dist[t] = 1e10f;
    sxyz[p] = make_float4(px[t], py[t], pz[t], 0.0f);
  }
  __syncthreads();
  int far = 0;                                      // reference: idx[0] = 0
  for(int it = 0; it < S_; ++it){
    float4 c = sxyz[far];                           // broadcast b128 read
    if(tid == 0){
      float* o = out_newxyz + ((size_t)b * S_ + it) * 3;
      o[0] = c.x; o[1] = c.y; o[2] = c.z;
    }
    if(it == S_ - 1) break;
    float bestd = -1.0f; int bestt = 0;
#pragma unroll
    for(int t = 0; t < 16; ++t){
      float d;
      {
#pragma clang fp contract(off)
        float dx = px[t] - c.x, dy = py[t] - c.y, dz = pz[t] - c.z;
        d = dx*dx + dy*dy + dz*dz;   // match reference: plain mul/add, left-to-right
      }
      float nd = fminf(dist[t], d);
      dist[t] = nd;
      if(nd > bestd){ bestd = nd; bestt = t; }      // ascending idx -> first max
    }
    const int bestp = tid + (bestt << 8);
    unsigned long long key = ((unsigned long long)__float_as_uint(bestd) << 32)
                           | (unsigned long long)(uint32_t)(~bestp);
    DPP_MAXSTEP(key, 0x111);
    DPP_MAXSTEP(key, 0x112);
    DPP_MAXSTEP(key, 0x114);
    DPP_MAXSTEP(key, 0x118);
    DPP_MAXSTEP(key, 0x142);
    DPP_MAXSTEP(key, 0x143);                        // lane 63 holds wave max
    const int par = it & 1;
    if((tid & 63) == 63) slots[par][tid >> 6] = key;
    __syncthreads();
    const unsigned long long* sp = slots[par];
    unsigned long long bk = sp[0];
#pragma unroll
    for(int w = 1; w < 4; ++w){
      unsigned long long ok = sp[w];
      if(ok > bk) bk = ok;
    }
    far = (int)(~(uint32_t)bk);                     // uniform across block
  }
}

// ---------------------------------------------------------------------------
// 2) Ball query with fp32 prefilter. Rigorous bound: fp32 eval of sq has
//    abs err < 2e-6 (intermediates <= 6, <= 8 roundings). Band = 5e-5 (25x
//    margin). If ANY lane is in-band, the whole wave takes the exact fp64
//    path (uniform branch, decisions for non-band lanes identical either
//    way) -- ~0.7% of chunks. Decisions provably identical to the verified
//    round-3 fp64 kernel.
// ---------------------------------------------------------------------------
__global__ __launch_bounds__(256) void ballq_kernel(const float* __restrict__ xyz,
                                                    const float* __restrict__ newxyz,
                                                    int* __restrict__ gidx){
  const int wslot = threadIdx.x >> 6;
  const int lane  = threadIdx.x & 63;
  const int q = blockIdx.x * 4 + wslot;
  const int b = q >> 10;
  const float* X = xyz + (size_t)b * N_ * 3;
  const double R2D = 0.2 * 0.2;                // == Python 0.2**2
  float nxf, nyf, nzf, saf;
  double nx, ny, nz, sa;
  {
    const float* NP = newxyz + (size_t)q * 3;
    nxf = NP[0]; nyf = NP[1]; nzf = NP[2];
    saf = nxf*nxf + nyf*nyf + nzf*nzf;
    nx = (double)nxf; ny = (double)nyf; nz = (double)nzf;
    sa = nx*nx + ny*ny + nz*nz;
  }
  __shared__ int sidx[4][K_];
  int count = 0;
  for(int base = 0; base < N_; base += 64){
    int p = base + lane;
    float pxf = X[p*3 + 0], pyf = X[p*3 + 1], pzf = X[p*3 + 2];
    float sb32 = pxf*pxf + pyf*pyf + pzf*pzf;
    float dt32 = nxf*pxf + nyf*pyf + nzf*pzf;
    float sq32 = saf + sb32 - 2.0f * dt32;
    bool band = fabsf(sq32 - 0.04f) < 5e-5f;
    bool inb;
    if(__ballot(band) != 0ull){
      // exact fp64 path, identical expression/order to the verified kernel
      double pxv = (double)pxf, pyv = (double)pyf, pzv = (double)pzf;
      double sb = pxv*pxv + pyv*pyv + pzv*pzv;
      double dt = nx*pxv + ny*pyv + nz*pzv;
      double sq = sa + sb - 2.0 * dt;
      inb = !(sq > R2D);
    } else {
      inb = !(sq32 > 0.04f);
    }
    unsigned long long mask = __ballot(inb);
    int pos = count + __popcll(mask & ((1ull << lane) - 1ull));
    if(inb && pos < K_) sidx[wslot][pos] = p;
    count += (int)__popcll(mask);
    if(count >= K_) break;
  }
  __syncthreads();
  int nvalid = count < K_ ? count : K_;
  if(lane < K_){
    int first = sidx[wslot][0];
    int v = (lane < nvalid) ? sidx[wslot][lane] : first;
    gidx[(size_t)q * K_ + lane] = v;
  }
}

// ---------------------------------------------------------------------------
// 3) Layer 1: gather + concat + GEMM (67->64) + bias -> y1t[m][c] bf16,
//    fused stats0. Unchanged from round 8/9 (verified).
// ---------------------------------------------------------------------------
__global__ __launch_bounds__(256)
void layer1_kernel(const float* __restrict__ xyz,
                   const float* __restrict__ pts,
                   const float* __restrict__ newxyz,
                   const int* __restrict__ gidx,
                   const float* __restrict__ w,
                   const float* __restrict__ bias,
                   uint16_t* __restrict__ y1t,
                   float* __restrict__ gstats){
  __shared__ float sm_sum[64*33];
  __shared__ float sm_sq [64*33];
  const int tid = threadIdx.x;
  for(int i = tid; i < 64*33; i += 256){ sm_sum[i] = 0.f; sm_sq[i] = 0.f; }
  __syncthreads();

  const int m = blockIdx.x * 256 + tid;
  const int bs = m >> 5;
  const int b  = bs >> 10;
  const int j  = gidx[m];
  float x[67];
  {
    const float* nxp = newxyz + (size_t)bs * 3;
    const float* pp  = xyz + ((size_t)b * N_ + j) * 3;
    x[0] = pp[0] - nxp[0]; x[1] = pp[1] - nxp[1]; x[2] = pp[2] - nxp[2];
  }
  {
    const float4* pr = (const float4*)(pts + ((size_t)b * N_ + j) * D_);
#pragma unroll
    for(int c4 = 0; c4 < 16; ++c4){
      float4 v = pr[c4];
      x[3 + c4*4 + 0] = v.x; x[3 + c4*4 + 1] = v.y;
      x[3 + c4*4 + 2] = v.z; x[3 + c4*4 + 3] = v.w;
    }
  }
  const int col = tid & 31;
  for(int o = 0; o < 64; ++o){
    float acc = bias[o];
#pragma unroll
    for(int c = 0; c < 67; ++c) acc = fmaf(w[o*67 + c], x[c], acc);
    y1t[(size_t)m * 64 + o] = f2bf(acc);
    atomicAdd(&sm_sum[o*33 + col], acc);
    atomicAdd(&sm_sq [o*33 + col], acc*acc);
  }
  __syncthreads();
  if(tid < 64){
    float s = 0.f;
#pragma unroll
    for(int c = 0; c < 32; ++c) s += sm_sum[tid*33 + c];
    atomicAdd(&gstats[tid], s);
  } else if(tid < 128){
    int o = tid - 64; float s = 0.f;
#pragma unroll
    for(int c = 0; c < 32; ++c) s += sm_sq[o*33 + c];
    atomicAdd(&gstats[64 + o], s);
  }
}

// ---------------------------------------------------------------------------
// 4) Layer 2 stats via MFMA (verified round 8). Same mfma order as layer3's
//    recompute => bitwise-identical z2.
// ---------------------------------------------------------------------------
__global__ __launch_bounds__(256)
void layer2_stats_kernel(const uint16_t* __restrict__ y1t,
                         const float* __restrict__ gstats0,
                         const float* __restrict__ g0,
                         const float* __restrict__ bt0,
                         const float* __restrict__ w1,
                         const float* __restrict__ b1,
                         float* __restrict__ gstats1){
  __shared__ short w1b[64*WPAD];
  __shared__ float la0s[64], lb0s[64], b1s[64];
  __shared__ float ssum[64], ssq[64];
  const int tid = threadIdx.x;
#pragma unroll
  for(int i = 0; i < 16; ++i){
    int e = i*256 + tid;
    w1b[(e>>6)*WPAD + (e&63)] = (short)f2bf(w1[e]);
  }
  if(tid < 64){
    float mean = gstats0[tid] * (1.0f / M_);
    float var  = gstats0[64 + tid] * (1.0f / M_) - mean * mean;
    float inv  = 1.0f / sqrtf(var + EPS_);
    float a = g0[tid] * inv;
    la0s[tid] = a; lb0s[tid] = bt0[tid] - mean * a;
    b1s[tid] = b1[tid];
  } else if(tid < 128){
    ssum[tid-64] = 0.f; ssq[tid-64] = 0.f;
  }
  __syncthreads();

  const int wave = tid >> 6, lane = tid & 63;
  const int row = lane & 15, quad = lane >> 4;
  const int wm0 = blockIdx.x * 128 + wave * 32;

  bf16x8 afr[2][2];
#pragma unroll
  for(int s = 0; s < 2; ++s)
#pragma unroll
    for(int k2 = 0; k2 < 2; ++k2)
      afr[s][k2] = h1_frag(y1t, la0s, lb0s, wm0 + s*16 + row, quad*8 + k2*32);

  for(int ot = 0; ot < 4; ++ot){
    bf16x8 bfr0 = *(const bf16x8*)&w1b[(ot*16 + row)*WPAD + quad*8];
    bf16x8 bfr1 = *(const bf16x8*)&w1b[(ot*16 + row)*WPAD + quad*8 + 32];
    const float bb = b1s[ot*16 + row];
    float sum_ = 0.f, sq_ = 0.f;
#pragma unroll
    for(int s = 0; s < 2; ++s){
      f32x4 acc = {0.f, 0.f, 0.f, 0.f};
      acc = __builtin_amdgcn_mfma_f32_16x16x32_bf16(afr[s][0], bfr0, acc, 0, 0, 0);
      acc = __builtin_amdgcn_mfma_f32_16x16x32_bf16(afr[s][1], bfr1, acc, 0, 0, 0);
#pragma unroll
      for(int r = 0; r < 4; ++r){
        float z = acc[r] + bb;
        sum_ += z; sq_ = fmaf(z, z, sq_);
      }
    }
    sum_ += __shfl_xor(sum_, 16, 64); sum_ += __shfl_xor(sum_, 32, 64);
    sq_  += __shfl_xor(sq_,  16, 64); sq_  += __shfl_xor(sq_,  32, 64);
    if(quad == 0){
      atomicAdd(&ssum[ot*16 + row], sum_);
      atomicAdd(&ssq [ot*16 + row], sq_);
    }
  }
  __syncthreads();
  if(tid < 64)       atomicAdd(&gstats1[tid], ssum[tid]);
  else if(tid < 128) atomicAdd(&gstats1[tid], ssq[tid - 64]);
}

// ---------------------------------------------------------------------------
// 5) Layer 3 via MFMA (verified round 8). Recompute z2 (identical order),
//    BN1+ReLU -> h2 LDS, L3 GEMM with fused stats2 + k-group max/min.
// ---------------------------------------------------------------------------
__global__ __launch_bounds__(256)
void layer3_kernel(const uint16_t* __restrict__ y1t,
                   const float* __restrict__ gstats0,
                   const float* __restrict__ g0,
                   const float* __restrict__ bt0,
                   const float* __restrict__ w1,
                   const float* __restrict__ b1,
                   const float* __restrict__ gstats1,
                   const float* __restrict__ g1,
                   const float* __restrict__ bt1,
                   const float* __restrict__ w2,
                   const float* __restrict__ b2,
                   float* __restrict__ gstats2,
                   float* __restrict__ maxk,
                   float* __restrict__ mink){
  __shared__ short w1b[64*WPAD];
  __shared__ short w2b[128*WPAD];
  __shared__ short h2s[4][32*WPAD];
  __shared__ float la0s[64], lb0s[64], la1s[64], lb1s[64], b1s[64], b2s[128];
  __shared__ float ssum[128], ssq[128];
  const int tid = threadIdx.x;
#pragma unroll
  for(int i = 0; i < 16; ++i){
    int e = i*256 + tid;
    w1b[(e>>6)*WPAD + (e&63)] = (short)f2bf(w1[e]);
  }
#pragma unroll
  for(int i = 0; i < 32; ++i){
    int e = i*256 + tid;
    w2b[(e>>6)*WPAD + (e&63)] = (short)f2bf(w2[e]);
  }
  if(tid < 64){
    float mean = gstats0[tid] * (1.0f / M_);
    float var  = gstats0[64 + tid] * (1.0f / M_) - mean * mean;
    float inv  = 1.0f / sqrtf(var + EPS_);
    float a = g0[tid] * inv;
    la0s[tid] = a; lb0s[tid] = bt0[tid] - mean * a;
    b1s[tid] = b1[tid];
  } else if(tid < 128){
    int o = tid - 64;
    float mean = gstats1[o] * (1.0f / M_);
    float var  = gstats1[64 + o] * (1.0f / M_) - mean * mean;
    float inv  = 1.0f / sqrtf(var + EPS_);
    float a = g1[o] * inv;
    la1s[o] = a; lb1s[o] = bt1[o] - mean * a;
  }
  if(tid < 128){ b2s[tid] = b2[tid]; ssum[tid] = 0.f; }
  else         { ssq[tid - 128] = 0.f; }
  __syncthreads();

  const int wave = tid >> 6, lane = tid & 63;
  const int row = lane & 15, quad = lane >> 4;
  const int wm0 = blockIdx.x * 128 + wave * 32;
  short* h2w = &h2s[wave][0];

  {
    bf16x8 afr[2][2];
#pragma unroll
    for(int s = 0; s < 2; ++s)
#pragma unroll
      for(int k2 = 0; k2 < 2; ++k2)
        afr[s][k2] = h1_frag(y1t, la0s, lb0s, wm0 + s*16 + row, quad*8 + k2*32);

    for(int ot = 0; ot < 4; ++ot){
      bf16x8 bfr0 = *(const bf16x8*)&w1b[(ot*16 + row)*WPAD + quad*8];
      bf16x8 bfr1 = *(const bf16x8*)&w1b[(ot*16 + row)*WPAD + quad*8 + 32];
      const int o = ot*16 + row;
      const float bb = b1s[o], a1 = la1s[o], c1 = lb1s[o];
#pragma unroll
      for(int s = 0; s < 2; ++s){
        f32x4 acc = {0.f, 0.f, 0.f, 0.f};
        acc = __builtin_amdgcn_mfma_f32_16x16x32_bf16(afr[s][0], bfr0, acc, 0, 0, 0);
        acc = __builtin_amdgcn_mfma_f32_16x16x32_bf16(afr[s][1], bfr1, acc, 0, 0, 0);
#pragma unroll
        for(int r = 0; r < 4; ++r){
          float z = acc[r] + bb;
          float h = fmaxf(a1 * z + c1, 0.0f);
          int ml = s*16 + quad*4 + r;
          h2w[ml*WPAD + o] = (short)f2bf(h);
        }
      }
    }
  }
  {
    bf16x8 hfr[2][2];
#pragma unroll
    for(int s = 0; s < 2; ++s)
#pragma unroll
      for(int k2 = 0; k2 < 2; ++k2)
        hfr[s][k2] = *(const bf16x8*)&h2w[(s*16 + row)*WPAD + quad*8 + k2*32];

    for(int ot = 0; ot < 8; ++ot){
      bf16x8 bfr0 = *(const bf16x8*)&w2b[(ot*16 + row)*WPAD + quad*8];
      bf16x8 bfr1 = *(const bf16x8*)&w2b[(ot*16 + row)*WPAD + quad*8 + 32];
      const int o = ot*16 + row;
      const float bb = b2s[o];
      float sum_ = 0.f, sq_ = 0.f, mx = -1e30f, mn = 1e30f;
#pragma unroll
      for(int s = 0; s < 2; ++s){
        f32x4 acc = {0.f, 0.f, 0.f, 0.f};
        acc = __builtin_amdgcn_mfma_f32_16x16x32_bf16(hfr[s][0], bfr0, acc, 0, 0, 0);
        acc = __builtin_amdgcn_mfma_f32_16x16x32_bf16(hfr[s][1], bfr1, acc, 0, 0, 0);
#pragma unroll
        for(int r = 0; r < 4; ++r){
          float z = acc[r] + bb;
          sum_ += z; sq_ = fmaf(z, z, sq_);
          mx = fmaxf(mx, z); mn = fminf(mn, z);
        }
      }
      sum_ += __shfl_xor(sum_, 16, 64); sum_ += __shfl_xor(sum_, 32, 64);
      sq_  += __shfl_xor(sq_,  16, 64); sq_  += __shfl_xor(sq_,  32, 64);
      mx = fmaxf(mx, __shfl_xor(mx, 16, 64)); mx = fmaxf(mx, __shfl_xor(mx, 32, 64));
      mn = fminf(mn, __shfl_xor(mn, 16, 64)); mn = fminf(mn, __shfl_xor(mn, 32, 64));
      if(quad == 0){
        atomicAdd(&ssum[o], sum_);
        atomicAdd(&ssq [o], sq_);
        maxk[(size_t)(wm0 >> 5) * 128 + o] = mx;
        mink[(size_t)(wm0 >> 5) * 128 + o] = mn;
      }
    }
  }
  __syncthreads();
  if(tid < 128) atomicAdd(&gstats2[tid], ssum[tid]);
  else          atomicAdd(&gstats2[tid], ssq[tid - 128]);
}

// ---------------------------------------------------------------------------
// 6) Final: BN2+ReLU on max/min endpoints. Unchanged.
// ---------------------------------------------------------------------------
__global__ __launch_bounds__(256) void final_kernel(const float* __restrict__ maxk,
                                                    const float* __restrict__ mink,
                                                    const float* __restrict__ gstats2,
                                                    const float* __restrict__ g,
                                                    const float* __restrict__ bt,
                                                    float* __restrict__ out_np){
  const int gid = blockIdx.x * 256 + threadIdx.x;
  const int o = gid & 127;
  float mean = gstats2[o] * (1.0f / M_);
  float var  = gstats2[128 + o] * (1.0f / M_) - mean * mean;
  float inv  = 1.0f / sqrtf(var + EPS_);
  float a = g[o] * inv;
  float b = bt[o] - mean * a;
  float mx = maxk[gid], mn = mink[gid];
  out_np[gid] = fmaxf(fmaxf(a * mx + b, 0.0f), fmaxf(a * mn + b, 0.0f));
}

// ---------------------------------------------------------------------------
extern "C" void kernel_launch(void* const* d_in, const int* in_sizes, int n_in,
                              void* d_out, int out_size, void* d_ws, size_t ws_size,
                              hipStream_t stream){
  (void)in_sizes; (void)n_in; (void)out_size;
  const float* xyz = (const float*)d_in[0];
  const float* pts = (const float*)d_in[1];
  const float* w0 = (const float*)d_in[2];  const float* b0  = (const float*)d_in[3];
  const float* g0 = (const float*)d_in[4];  const float* bt0 = (const float*)d_in[5];
  const float* w1 = (const float*)d_in[6];  const float* b1  = (const float*)d_in[7];
  const float* g1 = (const float*)d_in[8];  const float* bt1 = (const float*)d_in[9];
  const float* w2 = (const float*)d_in[10]; const float* b2  = (const float*)d_in[11];
  const float* g2 = (const float*)d_in[12]; const float* bt2 = (const float*)d_in[13];

  float* out    = (float*)d_out;
  float* newxyz = out;                       // (B,S,3)
  float* newpts = out + (size_t)B_ * S_ * 3; // (B,S,128)

  const size_t off_gidx  = 0;
  const size_t off_stats = off_gidx  + (size_t)M_ * 4;
  const size_t off_maxk  = off_stats + 65536;
  const size_t off_mink  = off_maxk  + (size_t)NQ_ * 128 * 4;
  const size_t off_y1    = off_mink  + (size_t)NQ_ * 128 * 4;
  const size_t need      = off_y1    + (size_t)M_ * 64 * 2;
  if(ws_size < need) return;

  char* ws = (char*)d_ws;
  int*      gidx   = (int*)     (ws + off_gidx);
  float*    gstats = (float*)   (ws + off_stats);
  float*    maxk   = (float*)   (ws + off_maxk);
  float*    mink   = (float*)   (ws + off_mink);
  uint16_t* y1t    = (uint16_t*)(ws + off_y1);

  zero_stats_kernel<<<2, 256, 0, stream>>>(gstats);
  fps_kernel  <<<B_, 256, 0, stream>>>(xyz, newxyz);
  ballq_kernel<<<NQ_ / 4, 256, 0, stream>>>(xyz, newxyz, gidx);

  layer1_kernel      <<<M_ / 256, 256, 0, stream>>>(xyz, pts, newxyz, gidx, w0, b0, y1t, gstats);
  layer2_stats_kernel<<<M_ / 128, 256, 0, stream>>>(y1t, gstats, g0, bt0, w1, b1, gstats + 128);
  layer3_kernel      <<<M_ / 128, 256, 0, stream>>>(y1t, gstats, g0, bt0, w1, b1,
                                                    gstats + 128, g1, bt1, w2, b2,
                                                    gstats + 256, maxk, mink);
  final_kernel<<<(NQ_ * 128) / 256, 256, 0, stream>>>(maxk, mink, gstats + 256, g2, bt2, newpts);
}

// Round 11
// 1325.425 us; speedup vs baseline: 1.1696x; 1.0078x over previous
//
#include <hip/hip_runtime.h>
#include <stdint.h>

#define B_ 16
#define N_ 4096
#define D_ 64
#define S_ 1024
#define K_ 32
#define M_ (B_*S_*K_)   /* 524288 */
#define NQ_ (B_*S_)     /* 16384 */
#define EPS_ 1e-5f
#define WPAD 72         /* bf16 LDS row stride: 72*2=144 B, 16B-aligned frags */

typedef short bf16x8 __attribute__((ext_vector_type(8)));
typedef float f32x4  __attribute__((ext_vector_type(4)));

static __device__ __forceinline__ float bf2f(uint16_t u){
  union{uint32_t i; float f;} v; v.i = ((uint32_t)u) << 16; return v.f;
}
static __device__ __forceinline__ uint16_t f2bf(float f){
  union{uint32_t i; float f;} v; v.f = f;
  uint32_t u = v.i;
  uint32_t r = (u + 0x7FFFu + ((u >> 16) & 1u)) >> 16;   // RNE, finite inputs
  return (uint16_t)r;
}

// One DPP max-combine step on a u64 key (verified bit-exact rounds 9-10).
#define DPP_MAXSTEP(k, CTRL) {                                                   \
  unsigned _lo = (unsigned)(k), _hi = (unsigned)((k) >> 32);                     \
  unsigned _plo = (unsigned)__builtin_amdgcn_update_dpp((int)_lo, (int)_lo,      \
                                                        CTRL, 0xf, 0xf, false); \
  unsigned _phi = (unsigned)__builtin_amdgcn_update_dpp((int)_hi, (int)_hi,      \
                                                        CTRL, 0xf, 0xf, false); \
  unsigned long long _pk = ((unsigned long long)_phi << 32) | _plo;              \
  if(_pk > (k)) (k) = _pk; }

// Build an MFMA A-fragment of h1 = relu(la0*y1 + lb0) in bf16 from y1t[m][c].
static __device__ __forceinline__ bf16x8 h1_frag(const uint16_t* __restrict__ y1t,
                                                 const float* la0s, const float* lb0s,
                                                 int m, int kb){
  const uint4 raw = *(const uint4*)(y1t + (size_t)m * 64 + kb);
  uint32_t wrd[4] = {raw.x, raw.y, raw.z, raw.w};
  bf16x8 f;
#pragma unroll
  for(int i = 0; i < 4; ++i){
    int c0 = kb + 2*i;
    float v0 = bf2f((uint16_t)(wrd[i] & 0xFFFFu));
    float v1 = bf2f((uint16_t)(wrd[i] >> 16));
    float h0 = fmaxf(la0s[c0]   * v0 + lb0s[c0],   0.0f);
    float h1 = fmaxf(la0s[c0+1] * v1 + lb0s[c0+1], 0.0f);
    f[2*i]   = (short)f2bf(h0);
    f[2*i+1] = (short)f2bf(h1);
  }
  return f;
}

// ---------------------------------------------------------------------------
// 0) Zero the global stats accumulators.
// ---------------------------------------------------------------------------
__global__ __launch_bounds__(256) void zero_stats_kernel(float* __restrict__ s){
  s[blockIdx.x * 256 + threadIdx.x] = 0.0f;   // grid 2 -> 512 floats
}

// ---------------------------------------------------------------------------
// 1) FPS: one block/batch, 256 threads, 16 pts/thread, DPP wave-argmax.
//    KEY FIX (r11): winner coords go to an LDS outbuf each iteration; the
//    global write happens ONCE after the loop. Previously tid0's per-iter
//    global store forced `s_waitcnt vmcnt(0)` before every s_barrier --
//    ~400 cyc/iter of store-drain stall for the whole block.
//    Distance math + argmax semantics bit-identical to rounds 3-10.
// ---------------------------------------------------------------------------
__global__ __launch_bounds__(256) void fps_kernel(const float* __restrict__ xyz,
                                                  float* __restrict__ out_newxyz){
  const int b = blockIdx.x;
  const int tid = threadIdx.x;
  const float* X = xyz + (size_t)b * N_ * 3;
  __shared__ float4 sxyz[N_];                       // 64 KB coord cache
  __shared__ unsigned long long slots[2][4];        // parity double-buffered
  __shared__ float outbuf[S_ * 3];                  // 12 KB result staging
  float px[16], py[16], pz[16], dist[16];
#pragma unroll
  for(int t = 0; t < 16; ++t){
    int p = tid + t * 256;
    px[t] = X[p*3 + 0]; py[t] = X[p*3 + 1]; pz[t] = X[p*3 + 2];
    dist[t] = 1e10f;
    sxyz[p] = make_float4(px[t], py[t], pz[t], 0.0f);
  }
  __syncthreads();
  int far = 0;                                      // reference: idx[0] = 0
  for(int it = 0; it < S_; ++it){
    float4 c = sxyz[far];                           // broadcast b128 read
    if(tid == 0){                                   // LDS only -- no vmcnt drain
      outbuf[it*3 + 0] = c.x; outbuf[it*3 + 1] = c.y; outbuf[it*3 + 2] = c.z;
    }
    if(it == S_ - 1) break;
    float bestd = -1.0f; int bestt = 0;
#pragma unroll
    for(int t = 0; t < 16; ++t){
      float d;
      {
#pragma clang fp contract(off)
        float dx = px[t] - c.x, dy = py[t] - c.y, dz = pz[t] - c.z;
        d = dx*dx + dy*dy + dz*dz;   // match reference: plain mul/add, left-to-right
      }
      float nd = fminf(dist[t], d);
      dist[t] = nd;
      if(nd > bestd){ bestd = nd; bestt = t; }      // ascending idx -> first max
    }
    const int bestp = tid + (bestt << 8);
    unsigned long long key = ((unsigned long long)__float_as_uint(bestd) << 32)
                           | (unsigned long long)(uint32_t)(~bestp);
    DPP_MAXSTEP(key, 0x111);
    DPP_MAXSTEP(key, 0x112);
    DPP_MAXSTEP(key, 0x114);
    DPP_MAXSTEP(key, 0x118);
    DPP_MAXSTEP(key, 0x142);
    DPP_MAXSTEP(key, 0x143);                        // lane 63 holds wave max
    const int par = it & 1;
    if((tid & 63) == 63) slots[par][tid >> 6] = key;
    __syncthreads();
    const unsigned long long* sp = slots[par];
    unsigned long long bk = sp[0];
#pragma unroll
    for(int w = 1; w < 4; ++w){
      unsigned long long ok = sp[w];
      if(ok > bk) bk = ok;
    }
    far = (int)(~(uint32_t)bk);                     // uniform across block
  }
  __syncthreads();
  float* O = out_newxyz + (size_t)b * S_ * 3;       // coalesced drain, once
  for(int i = tid; i < S_ * 3; i += 256) O[i] = outbuf[i];
}

// ---------------------------------------------------------------------------
// 2) Ball query with fp32 prefilter (r10-verified). Band 5e-5 >> 2e-6 fp32
//    error bound; any in-band lane sends the whole wave down the exact fp64
//    path. Decisions identical to the verified round-3 fp64 kernel.
// ---------------------------------------------------------------------------
__global__ __launch_bounds__(256) void ballq_kernel(const float* __restrict__ xyz,
                                                    const float* __restrict__ newxyz,
                                                    int* __restrict__ gidx){
  const int wslot = threadIdx.x >> 6;
  const int lane  = threadIdx.x & 63;
  const int q = blockIdx.x * 4 + wslot;
  const int b = q >> 10;
  const float* X = xyz + (size_t)b * N_ * 3;
  const double R2D = 0.2 * 0.2;
  float nxf, nyf, nzf, saf;
  double nx, ny, nz, sa;
  {
    const float* NP = newxyz + (size_t)q * 3;
    nxf = NP[0]; nyf = NP[1]; nzf = NP[2];
    saf = nxf*nxf + nyf*nyf + nzf*nzf;
    nx = (double)nxf; ny = (double)nyf; nz = (double)nzf;
    sa = nx*nx + ny*ny + nz*nz;
  }
  __shared__ int sidx[4][K_];
  int count = 0;
  for(int base = 0; base < N_; base += 64){
    int p = base + lane;
    float pxf = X[p*3 + 0], pyf = X[p*3 + 1], pzf = X[p*3 + 2];
    float sb32 = pxf*pxf + pyf*pyf + pzf*pzf;
    float dt32 = nxf*pxf + nyf*pyf + nzf*pzf;
    float sq32 = saf + sb32 - 2.0f * dt32;
    bool band = fabsf(sq32 - 0.04f) < 5e-5f;
    bool inb;
    if(__ballot(band) != 0ull){
      double pxv = (double)pxf, pyv = (double)pyf, pzv = (double)pzf;
      double sb = pxv*pxv + pyv*pyv + pzv*pzv;
      double dt = nx*pxv + ny*pyv + nz*pzv;
      double sq = sa + sb - 2.0 * dt;
      inb = !(sq > R2D);
    } else {
      inb = !(sq32 > 0.04f);
    }
    unsigned long long mask = __ballot(inb);
    int pos = count + __popcll(mask & ((1ull << lane) - 1ull));
    if(inb && pos < K_) sidx[wslot][pos] = p;
    count += (int)__popcll(mask);
    if(count >= K_) break;
  }
  __syncthreads();
  int nvalid = count < K_ ? count : K_;
  if(lane < K_){
    int first = sidx[wslot][0];
    int v = (lane < nvalid) ? sidx[wslot][lane] : first;
    gidx[(size_t)q * K_ + lane] = v;
  }
}

// ---------------------------------------------------------------------------
// 3) Layer 1: gather + concat + GEMM (67->64) + bias -> y1t[m][c] bf16.
//    KEY FIX (r11): o processed in 8 chunks of 8; each chunk's 8 bf16 are
//    packed into a uint4 and stored with ONE 16B instruction. The r8-r10
//    version issued 64 scattered 2-byte stores/thread (64 line-visits per
//    wave-store, ~33M L2 transactions). Same fp values/order; fused stats
//    unchanged -> output bit-identical.
// ---------------------------------------------------------------------------
__global__ __launch_bounds__(256)
void layer1_kernel(const float* __restrict__ xyz,
                   const float* __restrict__ pts,
                   const float* __restrict__ newxyz,
                   const int* __restrict__ gidx,
                   const float* __restrict__ w,
                   const float* __restrict__ bias,
                   uint16_t* __restrict__ y1t,
                   float* __restrict__ gstats){
  __shared__ float sm_sum[64*33];
  __shared__ float sm_sq [64*33];
  const int tid = threadIdx.x;
  for(int i = tid; i < 64*33; i += 256){ sm_sum[i] = 0.f; sm_sq[i] = 0.f; }
  __syncthreads();

  const int m = blockIdx.x * 256 + tid;
  const int bs = m >> 5;
  const int b  = bs >> 10;
  const int j  = gidx[m];
  float x[67];
  {
    const float* nxp = newxyz + (size_t)bs * 3;
    const float* pp  = xyz + ((size_t)b * N_ + j) * 3;
    x[0] = pp[0] - nxp[0]; x[1] = pp[1] - nxp[1]; x[2] = pp[2] - nxp[2];
  }
  {
    const float4* pr = (const float4*)(pts + ((size_t)b * N_ + j) * D_);
#pragma unroll
    for(int c4 = 0; c4 < 16; ++c4){
      float4 v = pr[c4];
      x[3 + c4*4 + 0] = v.x; x[3 + c4*4 + 1] = v.y;
      x[3 + c4*4 + 2] = v.z; x[3 + c4*4 + 3] = v.w;
    }
  }
  const int col = tid & 31;
  for(int oc = 0; oc < 8; ++oc){
    uint32_t packed[4];
#pragma unroll
    for(int oi = 0; oi < 8; ++oi){
      const int o = oc*8 + oi;
      float acc = bias[o];
#pragma unroll
      for(int c = 0; c < 67; ++c) acc = fmaf(w[o*67 + c], x[c], acc);
      atomicAdd(&sm_sum[o*33 + col], acc);
      atomicAdd(&sm_sq [o*33 + col], acc*acc);
      uint32_t h = (uint32_t)f2bf(acc);
      if(oi & 1) packed[oi >> 1] |= h << 16;
      else       packed[oi >> 1]  = h;
    }
    *(uint4*)(y1t + (size_t)m * 64 + oc*8) =
        make_uint4(packed[0], packed[1], packed[2], packed[3]);
  }
  __syncthreads();
  if(tid < 64){
    float s = 0.f;
#pragma unroll
    for(int c = 0; c < 32; ++c) s += sm_sum[tid*33 + c];
    atomicAdd(&gstats[tid], s);
  } else if(tid < 128){
    int o = tid - 64; float s = 0.f;
#pragma unroll
    for(int c = 0; c < 32; ++c) s += sm_sq[o*33 + c];
    atomicAdd(&gstats[64 + o], s);
  }
}

// ---------------------------------------------------------------------------
// 4) Layer 2 stats via MFMA (verified round 8). Same mfma order as layer3's
//    recompute => bitwise-identical z2.
// ---------------------------------------------------------------------------
__global__ __launch_bounds__(256)
void layer2_stats_kernel(const uint16_t* __restrict__ y1t,
                         const float* __restrict__ gstats0,
                         const float* __restrict__ g0,
                         const float* __restrict__ bt0,
                         const float* __restrict__ w1,
                         const float* __restrict__ b1,
                         float* __restrict__ gstats1){
  __shared__ short w1b[64*WPAD];
  __shared__ float la0s[64], lb0s[64], b1s[64];
  __shared__ float ssum[64], ssq[64];
  const int tid = threadIdx.x;
#pragma unroll
  for(int i = 0; i < 16; ++i){
    int e = i*256 + tid;
    w1b[(e>>6)*WPAD + (e&63)] = (short)f2bf(w1[e]);
  }
  if(tid < 64){
    float mean = gstats0[tid] * (1.0f / M_);
    float var  = gstats0[64 + tid] * (1.0f / M_) - mean * mean;
    float inv  = 1.0f / sqrtf(var + EPS_);
    float a = g0[tid] * inv;
    la0s[tid] = a; lb0s[tid] = bt0[tid] - mean * a;
    b1s[tid] = b1[tid];
  } else if(tid < 128){
    ssum[tid-64] = 0.f; ssq[tid-64] = 0.f;
  }
  __syncthreads();

  const int wave = tid >> 6, lane = tid & 63;
  const int row = lane & 15, quad = lane >> 4;
  const int wm0 = blockIdx.x * 128 + wave * 32;

  bf16x8 afr[2][2];
#pragma unroll
  for(int s = 0; s < 2; ++s)
#pragma unroll
    for(int k2 = 0; k2 < 2; ++k2)
      afr[s][k2] = h1_frag(y1t, la0s, lb0s, wm0 + s*16 + row, quad*8 + k2*32);

  for(int ot = 0; ot < 4; ++ot){
    bf16x8 bfr0 = *(const bf16x8*)&w1b[(ot*16 + row)*WPAD + quad*8];
    bf16x8 bfr1 = *(const bf16x8*)&w1b[(ot*16 + row)*WPAD + quad*8 + 32];
    const float bb = b1s[ot*16 + row];
    float sum_ = 0.f, sq_ = 0.f;
#pragma unroll
    for(int s = 0; s < 2; ++s){
      f32x4 acc = {0.f, 0.f, 0.f, 0.f};
      acc = __builtin_amdgcn_mfma_f32_16x16x32_bf16(afr[s][0], bfr0, acc, 0, 0, 0);
      acc = __builtin_amdgcn_mfma_f32_16x16x32_bf16(afr[s][1], bfr1, acc, 0, 0, 0);
#pragma unroll
      for(int r = 0; r < 4; ++r){
        float z = acc[r] + bb;
        sum_ += z; sq_ = fmaf(z, z, sq_);
      }
    }
    sum_ += __shfl_xor(sum_, 16, 64); sum_ += __shfl_xor(sum_, 32, 64);
    sq_  += __shfl_xor(sq_,  16, 64); sq_  += __shfl_xor(sq_,  32, 64);
    if(quad == 0){
      atomicAdd(&ssum[ot*16 + row], sum_);
      atomicAdd(&ssq [ot*16 + row], sq_);
    }
  }
  __syncthreads();
  if(tid < 64)       atomicAdd(&gstats1[tid], ssum[tid]);
  else if(tid < 128) atomicAdd(&gstats1[tid], ssq[tid - 64]);
}

// ---------------------------------------------------------------------------
// 5) Layer 3 via MFMA (verified round 8). Recompute z2 (identical order),
//    BN1+ReLU -> h2 LDS, L3 GEMM with fused stats2 + k-group max/min.
// ---------------------------------------------------------------------------
__global__ __launch_bounds__(256)
void layer3_kernel(const uint16_t* __restrict__ y1t,
                   const float* __restrict__ gstats0,
                   const float* __restrict__ g0,
                   const float* __restrict__ bt0,
                   const float* __restrict__ w1,
                   const float* __restrict__ b1,
                   const float* __restrict__ gstats1,
                   const float* __restrict__ g1,
                   const float* __restrict__ bt1,
                   const float* __restrict__ w2,
                   const float* __restrict__ b2,
                   float* __restrict__ gstats2,
                   float* __restrict__ maxk,
                   float* __restrict__ mink){
  __shared__ short w1b[64*WPAD];
  __shared__ short w2b[128*WPAD];
  __shared__ short h2s[4][32*WPAD];
  __shared__ float la0s[64], lb0s[64], la1s[64], lb1s[64], b1s[64], b2s[128];
  __shared__ float ssum[128], ssq[128];
  const int tid = threadIdx.x;
#pragma unroll
  for(int i = 0; i < 16; ++i){
    int e = i*256 + tid;
    w1b[(e>>6)*WPAD + (e&63)] = (short)f2bf(w1[e]);
  }
#pragma unroll
  for(int i = 0; i < 32; ++i){
    int e = i*256 + tid;
    w2b[(e>>6)*WPAD + (e&63)] = (short)f2bf(w2[e]);
  }
  if(tid < 64){
    float mean = gstats0[tid] * (1.0f / M_);
    float var  = gstats0[64 + tid] * (1.0f / M_) - mean * mean;
    float inv  = 1.0f / sqrtf(var + EPS_);
    float a = g0[tid] * inv;
    la0s[tid] = a; lb0s[tid] = bt0[tid] - mean * a;
    b1s[tid] = b1[tid];
  } else if(tid < 128){
    int o = tid - 64;
    float mean = gstats1[o] * (1.0f / M_);
    float var  = gstats1[64 + o] * (1.0f / M_) - mean * mean;
    float inv  = 1.0f / sqrtf(var + EPS_);
    float a = g1[o] * inv;
    la1s[o] = a; lb1s[o] = bt1[o] - mean * a;
  }
  if(tid < 128){ b2s[tid] = b2[tid]; ssum[tid] = 0.f; }
  else         { ssq[tid - 128] = 0.f; }
  __syncthreads();

  const int wave = tid >> 6, lane = tid & 63;
  const int row = lane & 15, quad = lane >> 4;
  const int wm0 = blockIdx.x * 128 + wave * 32;
  short* h2w = &h2s[wave][0];

  {
    bf16x8 afr[2][2];
#pragma unroll
    for(int s = 0; s < 2; ++s)
#pragma unroll
      for(int k2 = 0; k2 < 2; ++k2)
        afr[s][k2] = h1_frag(y1t, la0s, lb0s, wm0 + s*16 + row, quad*8 + k2*32);

    for(int ot = 0; ot < 4; ++ot){
      bf16x8 bfr0 = *(const bf16x8*)&w1b[(ot*16 + row)*WPAD + quad*8];
      bf16x8 bfr1 = *(const bf16x8*)&w1b[(ot*16 + row)*WPAD + quad*8 + 32];
      const int o = ot*16 + row;
      const float bb = b1s[o], a1 = la1s[o], c1 = lb1s[o];
#pragma unroll
      for(int s = 0; s < 2; ++s){
        f32x4 acc = {0.f, 0.f, 0.f, 0.f};
        acc = __builtin_amdgcn_mfma_f32_16x16x32_bf16(afr[s][0], bfr0, acc, 0, 0, 0);
        acc = __builtin_amdgcn_mfma_f32_16x16x32_bf16(afr[s][1], bfr1, acc, 0, 0, 0);
#pragma unroll
        for(int r = 0; r < 4; ++r){
          float z = acc[r] + bb;
          float h = fmaxf(a1 * z + c1, 0.0f);
          int ml = s*16 + quad*4 + r;
          h2w[ml*WPAD + o] = (short)f2bf(h);
        }
      }
    }
  }
  {
    bf16x8 hfr[2][2];
#pragma unroll
    for(int s = 0; s < 2; ++s)
#pragma unroll
      for(int k2 = 0; k2 < 2; ++k2)
        hfr[s][k2] = *(const bf16x8*)&h2w[(s*16 + row)*WPAD + quad*8 + k2*32];

    for(int ot = 0; ot < 8; ++ot){
      bf16x8 bfr0 = *(const bf16x8*)&w2b[(ot*16 + row)*WPAD + quad*8];
      bf16x8 bfr1 = *(const bf16x8*)&w2b[(ot*16 + row)*WPAD + quad*8 + 32];
      const int o = ot*16 + row;
      const float bb = b2s[o];
      float sum_ = 0.f, sq_ = 0.f, mx = -1e30f, mn = 1e30f;
#pragma unroll
      for(int s = 0; s < 2; ++s){
        f32x4 acc = {0.f, 0.f, 0.f, 0.f};
        acc = __builtin_amdgcn_mfma_f32_16x16x32_bf16(hfr[s][0], bfr0, acc, 0, 0, 0);
        acc = __builtin_amdgcn_mfma_f32_16x16x32_bf16(hfr[s][1], bfr1, acc, 0, 0, 0);
#pragma unroll
        for(int r = 0; r < 4; ++r){
          float z = acc[r] + bb;
          sum_ += z; sq_ = fmaf(z, z, sq_);
          mx = fmaxf(mx, z); mn = fminf(mn, z);
        }
      }
      sum_ += __shfl_xor(sum_, 16, 64); sum_ += __shfl_xor(sum_, 32, 64);
      sq_  += __shfl_xor(sq_,  16, 64); sq_  += __shfl_xor(sq_,  32, 64);
      mx = fmaxf(mx, __shfl_xor(mx, 16, 64)); mx = fmaxf(mx, __shfl_xor(mx, 32, 64));
      mn = fminf(mn, __shfl_xor(mn, 16, 64)); mn = fminf(mn, __shfl_xor(mn, 32, 64));
      if(quad == 0){
        atomicAdd(&ssum[o], sum_);
        atomicAdd(&ssq [o], sq_);
        maxk[(size_t)(wm0 >> 5) * 128 + o] = mx;
        mink[(size_t)(wm0 >> 5) * 128 + o] = mn;
      }
    }
  }
  __syncthreads();
  if(tid < 128) atomicAdd(&gstats2[tid], ssum[tid]);
  else          atomicAdd(&gstats2[tid], ssq[tid - 128]);
}

// ---------------------------------------------------------------------------
// 6) Final: BN2+ReLU on max/min endpoints. Unchanged.
// ---------------------------------------------------------------------------
__global__ __launch_bounds__(256) void final_kernel(const float* __restrict__ maxk,
                                                    const float* __restrict__ mink,
                                                    const float* __restrict__ gstats2,
                                                    const float* __restrict__ g,
                                                    const float* __restrict__ bt,
                                                    float* __restrict__ out_np){
  const int gid = blockIdx.x * 256 + threadIdx.x;
  const int o = gid & 127;
  float mean = gstats2[o] * (1.0f / M_);
  float var  = gstats2[128 + o] * (1.0f / M_) - mean * mean;
  float inv  = 1.0f / sqrtf(var + EPS_);
  float a = g[o] * inv;
  float b = bt[o] - mean * a;
  float mx = maxk[gid], mn = mink[gid];
  out_np[gid] = fmaxf(fmaxf(a * mx + b, 0.0f), fmaxf(a * mn + b, 0.0f));
}

// ---------------------------------------------------------------------------
extern "C" void kernel_launch(void* const* d_in, const int* in_sizes, int n_in,
                              void* d_out, int out_size, void* d_ws, size_t ws_size,
                              hipStream_t stream){
  (void)in_sizes; (void)n_in; (void)out_size;
  const float* xyz = (const float*)d_in[0];
  const float* pts = (const float*)d_in[1];
  const float* w0 = (const float*)d_in[2];  const float* b0  = (const float*)d_in[3];
  const float* g0 = (const float*)d_in[4];  const float* bt0 = (const float*)d_in[5];
  const float* w1 = (const float*)d_in[6];  const float* b1  = (const float*)d_in[7];
  const float* g1 = (const float*)d_in[8];  const float* bt1 = (const float*)d_in[9];
  const float* w2 = (const float*)d_in[10]; const float* b2  = (const float*)d_in[11];
  const float* g2 = (const float*)d_in[12]; const float* bt2 = (const float*)d_in[13];

  float* out    = (float*)d_out;
  float* newxyz = out;                       // (B,S,3)
  float* newpts = out + (size_t)B_ * S_ * 3; // (B,S,128)

  const size_t off_gidx  = 0;
  const size_t off_stats = off_gidx  + (size_t)M_ * 4;
  const size_t off_maxk  = off_stats + 65536;
  const size_t off_mink  = off_maxk  + (size_t)NQ_ * 128 * 4;
  const size_t off_y1    = off_mink  + (size_t)NQ_ * 128 * 4;
  const size_t need      = off_y1    + (size_t)M_ * 64 * 2;
  if(ws_size < need) return;

  char* ws = (char*)d_ws;
  int*      gidx   = (int*)     (ws + off_gidx);
  float*    gstats = (float*)   (ws + off_stats);
  float*    maxk   = (float*)   (ws + off_maxk);
  float*    mink   = (float*)   (ws + off_mink);
  uint16_t* y1t    = (uint16_t*)(ws + off_y1);

  zero_stats_kernel<<<2, 256, 0, stream>>>(gstats);
  fps_kernel  <<<B_, 256, 0, stream>>>(xyz, newxyz);
  ballq_kernel<<<NQ_ / 4, 256, 0, stream>>>(xyz, newxyz, gidx);

  layer1_kernel      <<<M_ / 256, 256, 0, stream>>>(xyz, pts, newxyz, gidx, w0, b0, y1t, gstats);
  layer2_stats_kernel<<<M_ / 128, 256, 0, stream>>>(y1t, gstats, g0, bt0, w1, b1, gstats + 128);
  layer3_kernel      <<<M_ / 128, 256, 0, stream>>>(y1t, gstats, g0, bt0, w1, b1,
                                                    gstats + 128, g1, bt1, w2, b2,
                                                    gstats + 256, maxk, mink);
  final_kernel<<<(NQ_ * 128) / 256, 256, 0, stream>>>(maxk, mink, gstats + 256, g2, bt2, newpts);
}

// Round 12
// 1204.392 us; speedup vs baseline: 1.2872x; 1.1005x over previous
//
#include <hip/hip_runtime.h>
#include <stdint.h>

#define B_ 16
#define N_ 4096
#define D_ 64
#define S_ 1024
#define K_ 32
#define M_ (B_*S_*K_)   /* 524288 */
#define NQ_ (B_*S_)     /* 16384 */
#define EPS_ 1e-5f
#define WPAD 72         /* bf16 LDS row stride: 72*2=144 B, 16B-aligned frags */

typedef short bf16x8 __attribute__((ext_vector_type(8)));
typedef float f32x4  __attribute__((ext_vector_type(4)));

struct F3 { float x, y, z; };   // 12 B -> global_load_dwordx3, coalesced

static __device__ __forceinline__ float bf2f(uint16_t u){
  union{uint32_t i; float f;} v; v.i = ((uint32_t)u) << 16; return v.f;
}
static __device__ __forceinline__ uint16_t f2bf(float f){
  union{uint32_t i; float f;} v; v.f = f;
  uint32_t u = v.i;
  uint32_t r = (u + 0x7FFFu + ((u >> 16) & 1u)) >> 16;   // RNE, finite inputs
  return (uint16_t)r;
}

// One DPP max-combine step on a u64 key (verified bit-exact rounds 9-11).
#define DPP_MAXSTEP(k, CTRL) {                                                   \
  unsigned _lo = (unsigned)(k), _hi = (unsigned)((k) >> 32);                     \
  unsigned _plo = (unsigned)__builtin_amdgcn_update_dpp((int)_lo, (int)_lo,      \
                                                        CTRL, 0xf, 0xf, false); \
  unsigned _phi = (unsigned)__builtin_amdgcn_update_dpp((int)_hi, (int)_hi,      \
                                                        CTRL, 0xf, 0xf, false); \
  unsigned long long _pk = ((unsigned long long)_phi << 32) | _plo;              \
  if(_pk > (k)) (k) = _pk; }

// Build an MFMA A-fragment of h1 = relu(la0*y1 + lb0) in bf16 from y1t[m][c].
static __device__ __forceinline__ bf16x8 h1_frag(const uint16_t* __restrict__ y1t,
                                                 const float* la0s, const float* lb0s,
                                                 int m, int kb){
  const uint4 raw = *(const uint4*)(y1t + (size_t)m * 64 + kb);
  uint32_t wrd[4] = {raw.x, raw.y, raw.z, raw.w};
  bf16x8 f;
#pragma unroll
  for(int i = 0; i < 4; ++i){
    int c0 = kb + 2*i;
    float v0 = bf2f((uint16_t)(wrd[i] & 0xFFFFu));
    float v1 = bf2f((uint16_t)(wrd[i] >> 16));
    float h0 = fmaxf(la0s[c0]   * v0 + lb0s[c0],   0.0f);
    float h1 = fmaxf(la0s[c0+1] * v1 + lb0s[c0+1], 0.0f);
    f[2*i]   = (short)f2bf(h0);
    f[2*i+1] = (short)f2bf(h1);
  }
  return f;
}

// ---------------------------------------------------------------------------
// 1) FPS: one block/batch, 256 threads, 16 pts/thread, DPP wave-argmax,
//    LDS outbuf (r11), slot reduce now via two ds_read_b128 (r12 micro-opt).
//    Distance math + argmax semantics bit-identical to rounds 3-11.
// ---------------------------------------------------------------------------
__global__ __launch_bounds__(256) void fps_kernel(const float* __restrict__ xyz,
                                                  float* __restrict__ out_newxyz){
  const int b = blockIdx.x;
  const int tid = threadIdx.x;
  const float* X = xyz + (size_t)b * N_ * 3;
  __shared__ float4 sxyz[N_];                       // 64 KB coord cache
  __shared__ __align__(16) unsigned long long slots[2][4];
  __shared__ float outbuf[S_ * 3];                  // 12 KB result staging
  float px[16], py[16], pz[16], dist[16];
#pragma unroll
  for(int t = 0; t < 16; ++t){
    int p = tid + t * 256;
    px[t] = X[p*3 + 0]; py[t] = X[p*3 + 1]; pz[t] = X[p*3 + 2];
    dist[t] = 1e10f;
    sxyz[p] = make_float4(px[t], py[t], pz[t], 0.0f);
  }
  __syncthreads();
  int far = 0;                                      // reference: idx[0] = 0
  for(int it = 0; it < S_; ++it){
    float4 c = sxyz[far];                           // broadcast b128 read
    if(tid == 0){                                   // LDS only
      outbuf[it*3 + 0] = c.x; outbuf[it*3 + 1] = c.y; outbuf[it*3 + 2] = c.z;
    }
    if(it == S_ - 1) break;
    float bestd = -1.0f; int bestt = 0;
#pragma unroll
    for(int t = 0; t < 16; ++t){
      float d;
      {
#pragma clang fp contract(off)
        float dx = px[t] - c.x, dy = py[t] - c.y, dz = pz[t] - c.z;
        d = dx*dx + dy*dy + dz*dz;   // match reference: plain mul/add, left-to-right
      }
      float nd = fminf(dist[t], d);
      dist[t] = nd;
      if(nd > bestd){ bestd = nd; bestt = t; }      // ascending idx -> first max
    }
    const int bestp = tid + (bestt << 8);
    unsigned long long key = ((unsigned long long)__float_as_uint(bestd) << 32)
                           | (unsigned long long)(uint32_t)(~bestp);
    DPP_MAXSTEP(key, 0x111);
    DPP_MAXSTEP(key, 0x112);
    DPP_MAXSTEP(key, 0x114);
    DPP_MAXSTEP(key, 0x118);
    DPP_MAXSTEP(key, 0x142);
    DPP_MAXSTEP(key, 0x143);                        // lane 63 holds wave max
    const int par = it & 1;
    if((tid & 63) == 63) slots[par][tid >> 6] = key;
    __syncthreads();
    ulonglong2 s01 = *(const ulonglong2*)&slots[par][0];   // 2x ds_read_b128
    ulonglong2 s23 = *(const ulonglong2*)&slots[par][2];
    unsigned long long bk = s01.x;
    if(s01.y > bk) bk = s01.y;
    if(s23.x > bk) bk = s23.x;
    if(s23.y > bk) bk = s23.y;
    far = (int)(~(uint32_t)bk);                     // uniform across block
  }
  __syncthreads();
  float* O = out_newxyz + (size_t)b * S_ * 3;       // coalesced drain, once
  for(int i = tid; i < S_ * 3; i += 256) O[i] = outbuf[i];
}

// ---------------------------------------------------------------------------
// 2) Ball query, fp32 prefilter (r10-verified decisions) + dwordx3 coalesced
//    point loads. Block 0 also zeroes the 512-float gstats region (replaces
//    the zero_stats kernel; layer1 only runs after ballq completes).
// ---------------------------------------------------------------------------
__global__ __launch_bounds__(256) void ballq_kernel(const float* __restrict__ xyz,
                                                    const float* __restrict__ newxyz,
                                                    int* __restrict__ gidx,
                                                    float* __restrict__ gstats){
  const int tid = threadIdx.x;
  if(blockIdx.x == 0){                // fold: zero stats (512 floats)
    gstats[tid] = 0.0f; gstats[256 + tid] = 0.0f;
  }
  const int wslot = tid >> 6;
  const int lane  = tid & 63;
  const int q = blockIdx.x * 4 + wslot;
  const int b = q >> 10;
  const F3* XP = (const F3*)(xyz + (size_t)b * N_ * 3);
  const double R2D = 0.2 * 0.2;
  float nxf, nyf, nzf, saf;
  double nx, ny, nz, sa;
  {
    const float* NP = newxyz + (size_t)q * 3;
    nxf = NP[0]; nyf = NP[1]; nzf = NP[2];
    saf = nxf*nxf + nyf*nyf + nzf*nzf;
    nx = (double)nxf; ny = (double)nyf; nz = (double)nzf;
    sa = nx*nx + ny*ny + nz*nz;
  }
  __shared__ int sidx[4][K_];
  int count = 0;
  for(int base = 0; base < N_; base += 64){
    int p = base + lane;
    F3 pt = XP[p];                                  // global_load_dwordx3
    float sb32 = pt.x*pt.x + pt.y*pt.y + pt.z*pt.z;
    float dt32 = nxf*pt.x + nyf*pt.y + nzf*pt.z;
    float sq32 = saf + sb32 - 2.0f * dt32;
    bool band = fabsf(sq32 - 0.04f) < 5e-5f;
    bool inb;
    if(__ballot(band) != 0ull){
      double pxv = (double)pt.x, pyv = (double)pt.y, pzv = (double)pt.z;
      double sb = pxv*pxv + pyv*pyv + pzv*pzv;
      double dt = nx*pxv + ny*pyv + nz*pzv;
      double sq = sa + sb - 2.0 * dt;
      inb = !(sq > R2D);
    } else {
      inb = !(sq32 > 0.04f);
    }
    unsigned long long mask = __ballot(inb);
    int pos = count + __popcll(mask & ((1ull << lane) - 1ull));
    if(inb && pos < K_) sidx[wslot][pos] = p;
    count += (int)__popcll(mask);
    if(count >= K_) break;
  }
  __syncthreads();
  int nvalid = count < K_ ? count : K_;
  if(lane < K_){
    int first = sidx[wslot][0];
    int v = (lane < nvalid) ? sidx[wslot][lane] : first;
    gidx[(size_t)q * K_ + lane] = v;
  }
}

// ---------------------------------------------------------------------------
// 3) Layer 1: gather + concat + GEMM (67->64) + bias -> y1t[m][c] bf16
//    (uint4-packed 16B stores, r11) + fused stats0. Unchanged from r11.
// ---------------------------------------------------------------------------
__global__ __launch_bounds__(256)
void layer1_kernel(const float* __restrict__ xyz,
                   const float* __restrict__ pts,
                   const float* __restrict__ newxyz,
                   const int* __restrict__ gidx,
                   const float* __restrict__ w,
                   const float* __restrict__ bias,
                   uint16_t* __restrict__ y1t,
                   float* __restrict__ gstats){
  __shared__ float sm_sum[64*33];
  __shared__ float sm_sq [64*33];
  const int tid = threadIdx.x;
  for(int i = tid; i < 64*33; i += 256){ sm_sum[i] = 0.f; sm_sq[i] = 0.f; }
  __syncthreads();

  const int m = blockIdx.x * 256 + tid;
  const int bs = m >> 5;
  const int b  = bs >> 10;
  const int j  = gidx[m];
  float x[67];
  {
    const float* nxp = newxyz + (size_t)bs * 3;
    const float* pp  = xyz + ((size_t)b * N_ + j) * 3;
    x[0] = pp[0] - nxp[0]; x[1] = pp[1] - nxp[1]; x[2] = pp[2] - nxp[2];
  }
  {
    const float4* pr = (const float4*)(pts + ((size_t)b * N_ + j) * D_);
#pragma unroll
    for(int c4 = 0; c4 < 16; ++c4){
      float4 v = pr[c4];
      x[3 + c4*4 + 0] = v.x; x[3 + c4*4 + 1] = v.y;
      x[3 + c4*4 + 2] = v.z; x[3 + c4*4 + 3] = v.w;
    }
  }
  const int col = tid & 31;
  for(int oc = 0; oc < 8; ++oc){
    uint32_t packed[4];
#pragma unroll
    for(int oi = 0; oi < 8; ++oi){
      const int o = oc*8 + oi;
      float acc = bias[o];
#pragma unroll
      for(int c = 0; c < 67; ++c) acc = fmaf(w[o*67 + c], x[c], acc);
      atomicAdd(&sm_sum[o*33 + col], acc);
      atomicAdd(&sm_sq [o*33 + col], acc*acc);
      uint32_t h = (uint32_t)f2bf(acc);
      if(oi & 1) packed[oi >> 1] |= h << 16;
      else       packed[oi >> 1]  = h;
    }
    *(uint4*)(y1t + (size_t)m * 64 + oc*8) =
        make_uint4(packed[0], packed[1], packed[2], packed[3]);
  }
  __syncthreads();
  if(tid < 64){
    float s = 0.f;
#pragma unroll
    for(int c = 0; c < 32; ++c) s += sm_sum[tid*33 + c];
    atomicAdd(&gstats[tid], s);
  } else if(tid < 128){
    int o = tid - 64; float s = 0.f;
#pragma unroll
    for(int c = 0; c < 32; ++c) s += sm_sq[o*33 + c];
    atomicAdd(&gstats[64 + o], s);
  }
}

// ---------------------------------------------------------------------------
// 4) Layer 2 stats via MFMA, r12: 512 m per block (4 chunks) to amortize the
//    weight-staging preamble 4x (was one 16-iter convert+stage per 128 m).
//    Same mfma order as layer3's recompute => bitwise-identical z2.
// ---------------------------------------------------------------------------
__global__ __launch_bounds__(256)
void layer2_stats_kernel(const uint16_t* __restrict__ y1t,
                         const float* __restrict__ gstats0,
                         const float* __restrict__ g0,
                         const float* __restrict__ bt0,
                         const float* __restrict__ w1,
                         const float* __restrict__ b1,
                         float* __restrict__ gstats1){
  __shared__ short w1b[64*WPAD];
  __shared__ float la0s[64], lb0s[64], b1s[64];
  __shared__ float ssum[64], ssq[64];
  const int tid = threadIdx.x;
#pragma unroll
  for(int i = 0; i < 16; ++i){
    int e = i*256 + tid;
    w1b[(e>>6)*WPAD + (e&63)] = (short)f2bf(w1[e]);
  }
  if(tid < 64){
    float mean = gstats0[tid] * (1.0f / M_);
    float var  = gstats0[64 + tid] * (1.0f / M_) - mean * mean;
    float inv  = 1.0f / sqrtf(var + EPS_);
    float a = g0[tid] * inv;
    la0s[tid] = a; lb0s[tid] = bt0[tid] - mean * a;
    b1s[tid] = b1[tid];
  } else if(tid < 128){
    ssum[tid-64] = 0.f; ssq[tid-64] = 0.f;
  }
  __syncthreads();

  const int wave = tid >> 6, lane = tid & 63;
  const int row = lane & 15, quad = lane >> 4;

  for(int ck = 0; ck < 4; ++ck){
    const int wm0 = blockIdx.x * 512 + ck * 128 + wave * 32;
    bf16x8 afr[2][2];
#pragma unroll
    for(int s = 0; s < 2; ++s)
#pragma unroll
      for(int k2 = 0; k2 < 2; ++k2)
        afr[s][k2] = h1_frag(y1t, la0s, lb0s, wm0 + s*16 + row, quad*8 + k2*32);

    for(int ot = 0; ot < 4; ++ot){
      bf16x8 bfr0 = *(const bf16x8*)&w1b[(ot*16 + row)*WPAD + quad*8];
      bf16x8 bfr1 = *(const bf16x8*)&w1b[(ot*16 + row)*WPAD + quad*8 + 32];
      const float bb = b1s[ot*16 + row];
      float sum_ = 0.f, sq_ = 0.f;
#pragma unroll
      for(int s = 0; s < 2; ++s){
        f32x4 acc = {0.f, 0.f, 0.f, 0.f};
        acc = __builtin_amdgcn_mfma_f32_16x16x32_bf16(afr[s][0], bfr0, acc, 0, 0, 0);
        acc = __builtin_amdgcn_mfma_f32_16x16x32_bf16(afr[s][1], bfr1, acc, 0, 0, 0);
#pragma unroll
        for(int r = 0; r < 4; ++r){
          float z = acc[r] + bb;
          sum_ += z; sq_ = fmaf(z, z, sq_);
        }
      }
      sum_ += __shfl_xor(sum_, 16, 64); sum_ += __shfl_xor(sum_, 32, 64);
      sq_  += __shfl_xor(sq_,  16, 64); sq_  += __shfl_xor(sq_,  32, 64);
      if(quad == 0){
        atomicAdd(&ssum[ot*16 + row], sum_);
        atomicAdd(&ssq [ot*16 + row], sq_);
      }
    }
  }
  __syncthreads();
  if(tid < 64)       atomicAdd(&gstats1[tid], ssum[tid]);
  else if(tid < 128) atomicAdd(&gstats1[tid], ssq[tid - 64]);
}

// ---------------------------------------------------------------------------
// 5) Layer 3 via MFMA, r12: 512 m per block (4 chunks). h2 staging is
//    wave-private LDS -> no inter-chunk barriers. Same mfma order as
//    layer2_stats => bitwise-identical z2; fused stats2 + k-group max/min.
// ---------------------------------------------------------------------------
__global__ __launch_bounds__(256)
void layer3_kernel(const uint16_t* __restrict__ y1t,
                   const float* __restrict__ gstats0,
                   const float* __restrict__ g0,
                   const float* __restrict__ bt0,
                   const float* __restrict__ w1,
                   const float* __restrict__ b1,
                   const float* __restrict__ gstats1,
                   const float* __restrict__ g1,
                   const float* __restrict__ bt1,
                   const float* __restrict__ w2,
                   const float* __restrict__ b2,
                   float* __restrict__ gstats2,
                   float* __restrict__ maxk,
                   float* __restrict__ mink){
  __shared__ short w1b[64*WPAD];
  __shared__ short w2b[128*WPAD];
  __shared__ short h2s[4][32*WPAD];
  __shared__ float la0s[64], lb0s[64], la1s[64], lb1s[64], b1s[64], b2s[128];
  __shared__ float ssum[128], ssq[128];
  const int tid = threadIdx.x;
#pragma unroll
  for(int i = 0; i < 16; ++i){
    int e = i*256 + tid;
    w1b[(e>>6)*WPAD + (e&63)] = (short)f2bf(w1[e]);
  }
#pragma unroll
  for(int i = 0; i < 32; ++i){
    int e = i*256 + tid;
    w2b[(e>>6)*WPAD + (e&63)] = (short)f2bf(w2[e]);
  }
  if(tid < 64){
    float mean = gstats0[tid] * (1.0f / M_);
    float var  = gstats0[64 + tid] * (1.0f / M_) - mean * mean;
    float inv  = 1.0f / sqrtf(var + EPS_);
    float a = g0[tid] * inv;
    la0s[tid] = a; lb0s[tid] = bt0[tid] - mean * a;
    b1s[tid] = b1[tid];
  } else if(tid < 128){
    int o = tid - 64;
    float mean = gstats1[o] * (1.0f / M_);
    float var  = gstats1[64 + o] * (1.0f / M_) - mean * mean;
    float inv  = 1.0f / sqrtf(var + EPS_);
    float a = g1[o] * inv;
    la1s[o] = a; lb1s[o] = bt1[o] - mean * a;
  }
  if(tid < 128){ b2s[tid] = b2[tid]; ssum[tid] = 0.f; }
  else         { ssq[tid - 128] = 0.f; }
  __syncthreads();

  const int wave = tid >> 6, lane = tid & 63;
  const int row = lane & 15, quad = lane >> 4;
  short* h2w = &h2s[wave][0];

  for(int ck = 0; ck < 4; ++ck){
    const int wm0 = blockIdx.x * 512 + ck * 128 + wave * 32;
    {
      bf16x8 afr[2][2];
#pragma unroll
      for(int s = 0; s < 2; ++s)
#pragma unroll
        for(int k2 = 0; k2 < 2; ++k2)
          afr[s][k2] = h1_frag(y1t, la0s, lb0s, wm0 + s*16 + row, quad*8 + k2*32);

      for(int ot = 0; ot < 4; ++ot){
        bf16x8 bfr0 = *(const bf16x8*)&w1b[(ot*16 + row)*WPAD + quad*8];
        bf16x8 bfr1 = *(const bf16x8*)&w1b[(ot*16 + row)*WPAD + quad*8 + 32];
        const int o = ot*16 + row;
        const float bb = b1s[o], a1 = la1s[o], c1 = lb1s[o];
#pragma unroll
        for(int s = 0; s < 2; ++s){
          f32x4 acc = {0.f, 0.f, 0.f, 0.f};
          acc = __builtin_amdgcn_mfma_f32_16x16x32_bf16(afr[s][0], bfr0, acc, 0, 0, 0);
          acc = __builtin_amdgcn_mfma_f32_16x16x32_bf16(afr[s][1], bfr1, acc, 0, 0, 0);
#pragma unroll
          for(int r = 0; r < 4; ++r){
            float z = acc[r] + bb;
            float h = fmaxf(a1 * z + c1, 0.0f);
            int ml = s*16 + quad*4 + r;
            h2w[ml*WPAD + o] = (short)f2bf(h);
          }
        }
      }
    }
    {
      bf16x8 hfr[2][2];
#pragma unroll
      for(int s = 0; s < 2; ++s)
#pragma unroll
        for(int k2 = 0; k2 < 2; ++k2)
          hfr[s][k2] = *(const bf16x8*)&h2w[(s*16 + row)*WPAD + quad*8 + k2*32];

      for(int ot = 0; ot < 8; ++ot){
        bf16x8 bfr0 = *(const bf16x8*)&w2b[(ot*16 + row)*WPAD + quad*8];
        bf16x8 bfr1 = *(const bf16x8*)&w2b[(ot*16 + row)*WPAD + quad*8 + 32];
        const int o = ot*16 + row;
        const float bb = b2s[o];
        float sum_ = 0.f, sq_ = 0.f, mx = -1e30f, mn = 1e30f;
#pragma unroll
        for(int s = 0; s < 2; ++s){
          f32x4 acc = {0.f, 0.f, 0.f, 0.f};
          acc = __builtin_amdgcn_mfma_f32_16x16x32_bf16(hfr[s][0], bfr0, acc, 0, 0, 0);
          acc = __builtin_amdgcn_mfma_f32_16x16x32_bf16(hfr[s][1], bfr1, acc, 0, 0, 0);
#pragma unroll
          for(int r = 0; r < 4; ++r){
            float z = acc[r] + bb;
            sum_ += z; sq_ = fmaf(z, z, sq_);
            mx = fmaxf(mx, z); mn = fminf(mn, z);
          }
        }
        sum_ += __shfl_xor(sum_, 16, 64); sum_ += __shfl_xor(sum_, 32, 64);
        sq_  += __shfl_xor(sq_,  16, 64); sq_  += __shfl_xor(sq_,  32, 64);
        mx = fmaxf(mx, __shfl_xor(mx, 16, 64)); mx = fmaxf(mx, __shfl_xor(mx, 32, 64));
        mn = fminf(mn, __shfl_xor(mn, 16, 64)); mn = fminf(mn, __shfl_xor(mn, 32, 64));
        if(quad == 0){
          atomicAdd(&ssum[o], sum_);
          atomicAdd(&ssq [o], sq_);
          maxk[(size_t)(wm0 >> 5) * 128 + o] = mx;
          mink[(size_t)(wm0 >> 5) * 128 + o] = mn;
        }
      }
    }
  }
  __syncthreads();
  if(tid < 128) atomicAdd(&gstats2[tid], ssum[tid]);
  else          atomicAdd(&gstats2[tid], ssq[tid - 128]);
}

// ---------------------------------------------------------------------------
// 6) Final: BN2+ReLU on max/min endpoints. Unchanged.
// ---------------------------------------------------------------------------
__global__ __launch_bounds__(256) void final_kernel(const float* __restrict__ maxk,
                                                    const float* __restrict__ mink,
                                                    const float* __restrict__ gstats2,
                                                    const float* __restrict__ g,
                                                    const float* __restrict__ bt,
                                                    float* __restrict__ out_np){
  const int gid = blockIdx.x * 256 + threadIdx.x;
  const int o = gid & 127;
  float mean = gstats2[o] * (1.0f / M_);
  float var  = gstats2[128 + o] * (1.0f / M_) - mean * mean;
  float inv  = 1.0f / sqrtf(var + EPS_);
  float a = g[o] * inv;
  float b = bt[o] - mean * a;
  float mx = maxk[gid], mn = mink[gid];
  out_np[gid] = fmaxf(fmaxf(a * mx + b, 0.0f), fmaxf(a * mn + b, 0.0f));
}

// ---------------------------------------------------------------------------
extern "C" void kernel_launch(void* const* d_in, const int* in_sizes, int n_in,
                              void* d_out, int out_size, void* d_ws, size_t ws_size,
                              hipStream_t stream){
  (void)in_sizes; (void)n_in; (void)out_size;
  const float* xyz = (const float*)d_in[0];
  const float* pts = (const float*)d_in[1];
  const float* w0 = (const float*)d_in[2];  const float* b0  = (const float*)d_in[3];
  const float* g0 = (const float*)d_in[4];  const float* bt0 = (const float*)d_in[5];
  const float* w1 = (const float*)d_in[6];  const float* b1  = (const float*)d_in[7];
  const float* g1 = (const float*)d_in[8];  const float* bt1 = (const float*)d_in[9];
  const float* w2 = (const float*)d_in[10]; const float* b2  = (const float*)d_in[11];
  const float* g2 = (const float*)d_in[12]; const float* bt2 = (const float*)d_in[13];

  float* out    = (float*)d_out;
  float* newxyz = out;                       // (B,S,3)
  float* newpts = out + (size_t)B_ * S_ * 3; // (B,S,128)

  const size_t off_gidx  = 0;
  const size_t off_stats = off_gidx  + (size_t)M_ * 4;
  const size_t off_maxk  = off_stats + 65536;
  const size_t off_mink  = off_maxk  + (size_t)NQ_ * 128 * 4;
  const size_t off_y1    = off_mink  + (size_t)NQ_ * 128 * 4;
  const size_t need      = off_y1    + (size_t)M_ * 64 * 2;
  if(ws_size < need) return;

  char* ws = (char*)d_ws;
  int*      gidx   = (int*)     (ws + off_gidx);
  float*    gstats = (float*)   (ws + off_stats);
  float*    maxk   = (float*)   (ws + off_maxk);
  float*    mink   = (float*)   (ws + off_mink);
  uint16_t* y1t    = (uint16_t*)(ws + off_y1);

  fps_kernel  <<<B_, 256, 0, stream>>>(xyz, newxyz);
  ballq_kernel<<<NQ_ / 4, 256, 0, stream>>>(xyz, newxyz, gidx, gstats);

  layer1_kernel      <<<M_ / 256, 256, 0, stream>>>(xyz, pts, newxyz, gidx, w0, b0, y1t, gstats);
  layer2_stats_kernel<<<M_ / 512, 256, 0, stream>>>(y1t, gstats, g0, bt0, w1, b1, gstats + 128);
  layer3_kernel      <<<M_ / 512, 256, 0, stream>>>(y1t, gstats, g0, bt0, w1, b1,
                                                    gstats + 128, g1, bt1, w2, b2,
                                                    gstats + 256, maxk, mink);
  final_kernel<<<(NQ_ * 128) / 256, 256, 0, stream>>>(maxk, mink, gstats + 256, g2, bt2, newpts);
}

// Round 13
// 1198.313 us; speedup vs baseline: 1.2937x; 1.0051x over previous
//
#include <hip/hip_runtime.h>
#include <stdint.h>

#define B_ 16
#define N_ 4096
#define D_ 64
#define S_ 1024
#define K_ 32
#define M_ (B_*S_*K_)   /* 524288 */
#define NQ_ (B_*S_)     /* 16384 */
#define EPS_ 1e-5f
#define WPAD 72         /* bf16 LDS row stride: 72*2=144 B, 16B-aligned frags */

typedef short bf16x8 __attribute__((ext_vector_type(8)));
typedef float f32x4  __attribute__((ext_vector_type(4)));
typedef float f32x2  __attribute__((ext_vector_type(2)));   // -> v_pk_* f32 ops

struct F3 { float x, y, z; };   // 12 B -> global_load_dwordx3, coalesced

static __device__ __forceinline__ float bf2f(uint16_t u){
  union{uint32_t i; float f;} v; v.i = ((uint32_t)u) << 16; return v.f;
}
static __device__ __forceinline__ uint16_t f2bf(float f){
  union{uint32_t i; float f;} v; v.f = f;
  uint32_t u = v.i;
  uint32_t r = (u + 0x7FFFu + ((u >> 16) & 1u)) >> 16;   // RNE, finite inputs
  return (uint16_t)r;
}

// One DPP max-combine step on a u64 key (verified bit-exact rounds 9-12).
#define DPP_MAXSTEP(k, CTRL) {                                                   \
  unsigned _lo = (unsigned)(k), _hi = (unsigned)((k) >> 32);                     \
  unsigned _plo = (unsigned)__builtin_amdgcn_update_dpp((int)_lo, (int)_lo,      \
                                                        CTRL, 0xf, 0xf, false); \
  unsigned _phi = (unsigned)__builtin_amdgcn_update_dpp((int)_hi, (int)_hi,      \
                                                        CTRL, 0xf, 0xf, false); \
  unsigned long long _pk = ((unsigned long long)_phi << 32) | _plo;              \
  if(_pk > (k)) (k) = _pk; }

// Build an MFMA A-fragment of h1 = relu(la0*y1 + lb0) in bf16 from y1t[m][c].
static __device__ __forceinline__ bf16x8 h1_frag(const uint16_t* __restrict__ y1t,
                                                 const float* la0s, const float* lb0s,
                                                 int m, int kb){
  const uint4 raw = *(const uint4*)(y1t + (size_t)m * 64 + kb);
  uint32_t wrd[4] = {raw.x, raw.y, raw.z, raw.w};
  bf16x8 f;
#pragma unroll
  for(int i = 0; i < 4; ++i){
    int c0 = kb + 2*i;
    float v0 = bf2f((uint16_t)(wrd[i] & 0xFFFFu));
    float v1 = bf2f((uint16_t)(wrd[i] >> 16));
    float h0 = fmaxf(la0s[c0]   * v0 + lb0s[c0],   0.0f);
    float h1 = fmaxf(la0s[c0+1] * v1 + lb0s[c0+1], 0.0f);
    f[2*i]   = (short)f2bf(h0);
    f[2*i+1] = (short)f2bf(h1);
  }
  return f;
}

// ---------------------------------------------------------------------------
// 1) FPS: one block/batch, 256 threads, 16 pts/thread held as 8 f32x2 pairs.
//    r13: distance update in packed <2 x float> math (v_pk_add/mul/min_f32
//    dual-issue) -- two independent IEEE fp32 ops per instruction, bitwise
//    identical per element; pair j = (t=2j lo, t=2j+1 hi), checked lo-first
//    with strict > so first-max/lowest-index tie semantics are unchanged.
//    DPP wave-argmax + LDS outbuf as in rounds 11-12.
// ---------------------------------------------------------------------------
__global__ __launch_bounds__(256) void fps_kernel(const float* __restrict__ xyz,
                                                  float* __restrict__ out_newxyz){
  const int b = blockIdx.x;
  const int tid = threadIdx.x;
  const float* X = xyz + (size_t)b * N_ * 3;
  __shared__ float4 sxyz[N_];                       // 64 KB coord cache
  __shared__ __align__(16) unsigned long long slots[2][4];
  __shared__ float outbuf[S_ * 3];                  // 12 KB result staging
  f32x2 px[8], py[8], pz[8], dist[8];
#pragma unroll
  for(int j = 0; j < 8; ++j){
    int p0 = tid + (2*j)   * 256;
    int p1 = tid + (2*j+1) * 256;
    px[j].x = X[p0*3 + 0]; px[j].y = X[p1*3 + 0];
    py[j].x = X[p0*3 + 1]; py[j].y = X[p1*3 + 1];
    pz[j].x = X[p0*3 + 2]; pz[j].y = X[p1*3 + 2];
    dist[j].x = 1e10f; dist[j].y = 1e10f;
    sxyz[p0] = make_float4(px[j].x, py[j].x, pz[j].x, 0.0f);
    sxyz[p1] = make_float4(px[j].y, py[j].y, pz[j].y, 0.0f);
  }
  __syncthreads();
  int far = 0;                                      // reference: idx[0] = 0
  for(int it = 0; it < S_; ++it){
    float4 c = sxyz[far];                           // broadcast b128 read
    if(tid == 0){                                   // LDS only
      outbuf[it*3 + 0] = c.x; outbuf[it*3 + 1] = c.y; outbuf[it*3 + 2] = c.z;
    }
    if(it == S_ - 1) break;
    f32x2 cx; cx.x = c.x; cx.y = c.x;
    f32x2 cy; cy.x = c.y; cy.y = c.y;
    f32x2 cz; cz.x = c.z; cz.y = c.z;
    float bestd = -1.0f; int bestt = 0;
#pragma unroll
    for(int j = 0; j < 8; ++j){
      f32x2 nd;
      {
#pragma clang fp contract(off)
        f32x2 dx = px[j] - cx, dy = py[j] - cy, dz = pz[j] - cz;
        f32x2 d  = dx*dx + dy*dy + dz*dz;   // ((dx2+dy2)+dz2), same assoc as scalar
        nd = __builtin_elementwise_min(dist[j], d);
      }
      dist[j] = nd;
      if(nd.x > bestd){ bestd = nd.x; bestt = 2*j; }      // t ascending ->
      if(nd.y > bestd){ bestd = nd.y; bestt = 2*j+1; }    // first max kept
    }
    const int bestp = tid + (bestt << 8);
    unsigned long long key = ((unsigned long long)__float_as_uint(bestd) << 32)
                           | (unsigned long long)(uint32_t)(~bestp);
    DPP_MAXSTEP(key, 0x111);
    DPP_MAXSTEP(key, 0x112);
    DPP_MAXSTEP(key, 0x114);
    DPP_MAXSTEP(key, 0x118);
    DPP_MAXSTEP(key, 0x142);
    DPP_MAXSTEP(key, 0x143);                        // lane 63 holds wave max
    const int par = it & 1;
    if((tid & 63) == 63) slots[par][tid >> 6] = key;
    __syncthreads();
    ulonglong2 s01 = *(const ulonglong2*)&slots[par][0];   // 2x ds_read_b128
    ulonglong2 s23 = *(const ulonglong2*)&slots[par][2];
    unsigned long long bk = s01.x;
    if(s01.y > bk) bk = s01.y;
    if(s23.x > bk) bk = s23.x;
    if(s23.y > bk) bk = s23.y;
    far = (int)(~(uint32_t)bk);                     // uniform across block
  }
  __syncthreads();
  float* O = out_newxyz + (size_t)b * S_ * 3;       // coalesced drain, once
  for(int i = tid; i < S_ * 3; i += 256) O[i] = outbuf[i];
}

// ---------------------------------------------------------------------------
// 2) Ball query, fp32 prefilter (r10-verified decisions) + dwordx3 coalesced
//    point loads; block 0 zeroes gstats (r12). Unchanged from r12.
// ---------------------------------------------------------------------------
__global__ __launch_bounds__(256) void ballq_kernel(const float* __restrict__ xyz,
                                                    const float* __restrict__ newxyz,
                                                    int* __restrict__ gidx,
                                                    float* __restrict__ gstats){
  const int tid = threadIdx.x;
  if(blockIdx.x == 0){                // fold: zero stats (512 floats)
    gstats[tid] = 0.0f; gstats[256 + tid] = 0.0f;
  }
  const int wslot = tid >> 6;
  const int lane  = tid & 63;
  const int q = blockIdx.x * 4 + wslot;
  const int b = q >> 10;
  const F3* XP = (const F3*)(xyz + (size_t)b * N_ * 3);
  const double R2D = 0.2 * 0.2;
  float nxf, nyf, nzf, saf;
  double nx, ny, nz, sa;
  {
    const float* NP = newxyz + (size_t)q * 3;
    nxf = NP[0]; nyf = NP[1]; nzf = NP[2];
    saf = nxf*nxf + nyf*nyf + nzf*nzf;
    nx = (double)nxf; ny = (double)nyf; nz = (double)nzf;
    sa = nx*nx + ny*ny + nz*nz;
  }
  __shared__ int sidx[4][K_];
  int count = 0;
  for(int base = 0; base < N_; base += 64){
    int p = base + lane;
    F3 pt = XP[p];                                  // global_load_dwordx3
    float sb32 = pt.x*pt.x + pt.y*pt.y + pt.z*pt.z;
    float dt32 = nxf*pt.x + nyf*pt.y + nzf*pt.z;
    float sq32 = saf + sb32 - 2.0f * dt32;
    bool band = fabsf(sq32 - 0.04f) < 5e-5f;
    bool inb;
    if(__ballot(band) != 0ull){
      double pxv = (double)pt.x, pyv = (double)pt.y, pzv = (double)pt.z;
      double sb = pxv*pxv + pyv*pyv + pzv*pzv;
      double dt = nx*pxv + ny*pyv + nz*pzv;
      double sq = sa + sb - 2.0 * dt;
      inb = !(sq > R2D);
    } else {
      inb = !(sq32 > 0.04f);
    }
    unsigned long long mask = __ballot(inb);
    int pos = count + __popcll(mask & ((1ull << lane) - 1ull));
    if(inb && pos < K_) sidx[wslot][pos] = p;
    count += (int)__popcll(mask);
    if(count >= K_) break;
  }
  __syncthreads();
  int nvalid = count < K_ ? count : K_;
  if(lane < K_){
    int first = sidx[wslot][0];
    int v = (lane < nvalid) ? sidx[wslot][lane] : first;
    gidx[(size_t)q * K_ + lane] = v;
  }
}

// ---------------------------------------------------------------------------
// 3) Layer 1: gather + concat + GEMM (67->64) + bias -> y1t[m][c] bf16
//    (uint4-packed 16B stores) + fused stats0. Unchanged from r11/r12.
// ---------------------------------------------------------------------------
__global__ __launch_bounds__(256)
void layer1_kernel(const float* __restrict__ xyz,
                   const float* __restrict__ pts,
                   const float* __restrict__ newxyz,
                   const int* __restrict__ gidx,
                   const float* __restrict__ w,
                   const float* __restrict__ bias,
                   uint16_t* __restrict__ y1t,
                   float* __restrict__ gstats){
  __shared__ float sm_sum[64*33];
  __shared__ float sm_sq [64*33];
  const int tid = threadIdx.x;
  for(int i = tid; i < 64*33; i += 256){ sm_sum[i] = 0.f; sm_sq[i] = 0.f; }
  __syncthreads();

  const int m = blockIdx.x * 256 + tid;
  const int bs = m >> 5;
  const int b  = bs >> 10;
  const int j  = gidx[m];
  float x[67];
  {
    const float* nxp = newxyz + (size_t)bs * 3;
    const float* pp  = xyz + ((size_t)b * N_ + j) * 3;
    x[0] = pp[0] - nxp[0]; x[1] = pp[1] - nxp[1]; x[2] = pp[2] - nxp[2];
  }
  {
    const float4* pr = (const float4*)(pts + ((size_t)b * N_ + j) * D_);
#pragma unroll
    for(int c4 = 0; c4 < 16; ++c4){
      float4 v = pr[c4];
      x[3 + c4*4 + 0] = v.x; x[3 + c4*4 + 1] = v.y;
      x[3 + c4*4 + 2] = v.z; x[3 + c4*4 + 3] = v.w;
    }
  }
  const int col = tid & 31;
  for(int oc = 0; oc < 8; ++oc){
    uint32_t packed[4];
#pragma unroll
    for(int oi = 0; oi < 8; ++oi){
      const int o = oc*8 + oi;
      float acc = bias[o];
#pragma unroll
      for(int c = 0; c < 67; ++c) acc = fmaf(w[o*67 + c], x[c], acc);
      atomicAdd(&sm_sum[o*33 + col], acc);
      atomicAdd(&sm_sq [o*33 + col], acc*acc);
      uint32_t h = (uint32_t)f2bf(acc);
      if(oi & 1) packed[oi >> 1] |= h << 16;
      else       packed[oi >> 1]  = h;
    }
    *(uint4*)(y1t + (size_t)m * 64 + oc*8) =
        make_uint4(packed[0], packed[1], packed[2], packed[3]);
  }
  __syncthreads();
  if(tid < 64){
    float s = 0.f;
#pragma unroll
    for(int c = 0; c < 32; ++c) s += sm_sum[tid*33 + c];
    atomicAdd(&gstats[tid], s);
  } else if(tid < 128){
    int o = tid - 64; float s = 0.f;
#pragma unroll
    for(int c = 0; c < 32; ++c) s += sm_sq[o*33 + c];
    atomicAdd(&gstats[64 + o], s);
  }
}

// ---------------------------------------------------------------------------
// 4) Layer 2 stats via MFMA, 512 m/block (r12). Same mfma order as layer3's
//    recompute => bitwise-identical z2.
// ---------------------------------------------------------------------------
__global__ __launch_bounds__(256)
void layer2_stats_kernel(const uint16_t* __restrict__ y1t,
                         const float* __restrict__ gstats0,
                         const float* __restrict__ g0,
                         const float* __restrict__ bt0,
                         const float* __restrict__ w1,
                         const float* __restrict__ b1,
                         float* __restrict__ gstats1){
  __shared__ short w1b[64*WPAD];
  __shared__ float la0s[64], lb0s[64], b1s[64];
  __shared__ float ssum[64], ssq[64];
  const int tid = threadIdx.x;
#pragma unroll
  for(int i = 0; i < 16; ++i){
    int e = i*256 + tid;
    w1b[(e>>6)*WPAD + (e&63)] = (short)f2bf(w1[e]);
  }
  if(tid < 64){
    float mean = gstats0[tid] * (1.0f / M_);
    float var  = gstats0[64 + tid] * (1.0f / M_) - mean * mean;
    float inv  = 1.0f / sqrtf(var + EPS_);
    float a = g0[tid] * inv;
    la0s[tid] = a; lb0s[tid] = bt0[tid] - mean * a;
    b1s[tid] = b1[tid];
  } else if(tid < 128){
    ssum[tid-64] = 0.f; ssq[tid-64] = 0.f;
  }
  __syncthreads();

  const int wave = tid >> 6, lane = tid & 63;
  const int row = lane & 15, quad = lane >> 4;

  for(int ck = 0; ck < 4; ++ck){
    const int wm0 = blockIdx.x * 512 + ck * 128 + wave * 32;
    bf16x8 afr[2][2];
#pragma unroll
    for(int s = 0; s < 2; ++s)
#pragma unroll
      for(int k2 = 0; k2 < 2; ++k2)
        afr[s][k2] = h1_frag(y1t, la0s, lb0s, wm0 + s*16 + row, quad*8 + k2*32);

    for(int ot = 0; ot < 4; ++ot){
      bf16x8 bfr0 = *(const bf16x8*)&w1b[(ot*16 + row)*WPAD + quad*8];
      bf16x8 bfr1 = *(const bf16x8*)&w1b[(ot*16 + row)*WPAD + quad*8 + 32];
      const float bb = b1s[ot*16 + row];
      float sum_ = 0.f, sq_ = 0.f;
#pragma unroll
      for(int s = 0; s < 2; ++s){
        f32x4 acc = {0.f, 0.f, 0.f, 0.f};
        acc = __builtin_amdgcn_mfma_f32_16x16x32_bf16(afr[s][0], bfr0, acc, 0, 0, 0);
        acc = __builtin_amdgcn_mfma_f32_16x16x32_bf16(afr[s][1], bfr1, acc, 0, 0, 0);
#pragma unroll
        for(int r = 0; r < 4; ++r){
          float z = acc[r] + bb;
          sum_ += z; sq_ = fmaf(z, z, sq_);
        }
      }
      sum_ += __shfl_xor(sum_, 16, 64); sum_ += __shfl_xor(sum_, 32, 64);
      sq_  += __shfl_xor(sq_,  16, 64); sq_  += __shfl_xor(sq_,  32, 64);
      if(quad == 0){
        atomicAdd(&ssum[ot*16 + row], sum_);
        atomicAdd(&ssq [ot*16 + row], sq_);
      }
    }
  }
  __syncthreads();
  if(tid < 64)       atomicAdd(&gstats1[tid], ssum[tid]);
  else if(tid < 128) atomicAdd(&gstats1[tid], ssq[tid - 64]);
}

// ---------------------------------------------------------------------------
// 5) Layer 3 via MFMA, 512 m/block (r12). h2 staging wave-private; same mfma
//    order as layer2_stats; fused stats2 + k-group max/min.
// ---------------------------------------------------------------------------
__global__ __launch_bounds__(256)
void layer3_kernel(const uint16_t* __restrict__ y1t,
                   const float* __restrict__ gstats0,
                   const float* __restrict__ g0,
                   const float* __restrict__ bt0,
                   const float* __restrict__ w1,
                   const float* __restrict__ b1,
                   const float* __restrict__ gstats1,
                   const float* __restrict__ g1,
                   const float* __restrict__ bt1,
                   const float* __restrict__ w2,
                   const float* __restrict__ b2,
                   float* __restrict__ gstats2,
                   float* __restrict__ maxk,
                   float* __restrict__ mink){
  __shared__ short w1b[64*WPAD];
  __shared__ short w2b[128*WPAD];
  __shared__ short h2s[4][32*WPAD];
  __shared__ float la0s[64], lb0s[64], la1s[64], lb1s[64], b1s[64], b2s[128];
  __shared__ float ssum[128], ssq[128];
  const int tid = threadIdx.x;
#pragma unroll
  for(int i = 0; i < 16; ++i){
    int e = i*256 + tid;
    w1b[(e>>6)*WPAD + (e&63)] = (short)f2bf(w1[e]);
  }
#pragma unroll
  for(int i = 0; i < 32; ++i){
    int e = i*256 + tid;
    w2b[(e>>6)*WPAD + (e&63)] = (short)f2bf(w2[e]);
  }
  if(tid < 64){
    float mean = gstats0[tid] * (1.0f / M_);
    float var  = gstats0[64 + tid] * (1.0f / M_) - mean * mean;
    float inv  = 1.0f / sqrtf(var + EPS_);
    float a = g0[tid] * inv;
    la0s[tid] = a; lb0s[tid] = bt0[tid] - mean * a;
    b1s[tid] = b1[tid];
  } else if(tid < 128){
    int o = tid - 64;
    float mean = gstats1[o] * (1.0f / M_);
    float var  = gstats1[64 + o] * (1.0f / M_) - mean * mean;
    float inv  = 1.0f / sqrtf(var + EPS_);
    float a = g1[o] * inv;
    la1s[o] = a; lb1s[o] = bt1[o] - mean * a;
  }
  if(tid < 128){ b2s[tid] = b2[tid]; ssum[tid] = 0.f; }
  else         { ssq[tid - 128] = 0.f; }
  __syncthreads();

  const int wave = tid >> 6, lane = tid & 63;
  const int row = lane & 15, quad = lane >> 4;
  short* h2w = &h2s[wave][0];

  for(int ck = 0; ck < 4; ++ck){
    const int wm0 = blockIdx.x * 512 + ck * 128 + wave * 32;
    {
      bf16x8 afr[2][2];
#pragma unroll
      for(int s = 0; s < 2; ++s)
#pragma unroll
        for(int k2 = 0; k2 < 2; ++k2)
          afr[s][k2] = h1_frag(y1t, la0s, lb0s, wm0 + s*16 + row, quad*8 + k2*32);

      for(int ot = 0; ot < 4; ++ot){
        bf16x8 bfr0 = *(const bf16x8*)&w1b[(ot*16 + row)*WPAD + quad*8];
        bf16x8 bfr1 = *(const bf16x8*)&w1b[(ot*16 + row)*WPAD + quad*8 + 32];
        const int o = ot*16 + row;
        const float bb = b1s[o], a1 = la1s[o], c1 = lb1s[o];
#pragma unroll
        for(int s = 0; s < 2; ++s){
          f32x4 acc = {0.f, 0.f, 0.f, 0.f};
          acc = __builtin_amdgcn_mfma_f32_16x16x32_bf16(afr[s][0], bfr0, acc, 0, 0, 0);
          acc = __builtin_amdgcn_mfma_f32_16x16x32_bf16(afr[s][1], bfr1, acc, 0, 0, 0);
#pragma unroll
          for(int r = 0; r < 4; ++r){
            float z = acc[r] + bb;
            float h = fmaxf(a1 * z + c1, 0.0f);
            int ml = s*16 + quad*4 + r;
            h2w[ml*WPAD + o] = (short)f2bf(h);
          }
        }
      }
    }
    {
      bf16x8 hfr[2][2];
#pragma unroll
      for(int s = 0; s < 2; ++s)
#pragma unroll
        for(int k2 = 0; k2 < 2; ++k2)
          hfr[s][k2] = *(const bf16x8*)&h2w[(s*16 + row)*WPAD + quad*8 + k2*32];

      for(int ot = 0; ot < 8; ++ot){
        bf16x8 bfr0 = *(const bf16x8*)&w2b[(ot*16 + row)*WPAD + quad*8];
        bf16x8 bfr1 = *(const bf16x8*)&w2b[(ot*16 + row)*WPAD + quad*8 + 32];
        const int o = ot*16 + row;
        const float bb = b2s[o];
        float sum_ = 0.f, sq_ = 0.f, mx = -1e30f, mn = 1e30f;
#pragma unroll
        for(int s = 0; s < 2; ++s){
          f32x4 acc = {0.f, 0.f, 0.f, 0.f};
          acc = __builtin_amdgcn_mfma_f32_16x16x32_bf16(hfr[s][0], bfr0, acc, 0, 0, 0);
          acc = __builtin_amdgcn_mfma_f32_16x16x32_bf16(hfr[s][1], bfr1, acc, 0, 0, 0);
#pragma unroll
          for(int r = 0; r < 4; ++r){
            float z = acc[r] + bb;
            sum_ += z; sq_ = fmaf(z, z, sq_);
            mx = fmaxf(mx, z); mn = fminf(mn, z);
          }
        }
        sum_ += __shfl_xor(sum_, 16, 64); sum_ += __shfl_xor(sum_, 32, 64);
        sq_  += __shfl_xor(sq_,  16, 64); sq_  += __shfl_xor(sq_,  32, 64);
        mx = fmaxf(mx, __shfl_xor(mx, 16, 64)); mx = fmaxf(mx, __shfl_xor(mx, 32, 64));
        mn = fminf(mn, __shfl_xor(mn, 16, 64)); mn = fminf(mn, __shfl_xor(mn, 32, 64));
        if(quad == 0){
          atomicAdd(&ssum[o], sum_);
          atomicAdd(&ssq [o], sq_);
          maxk[(size_t)(wm0 >> 5) * 128 + o] = mx;
          mink[(size_t)(wm0 >> 5) * 128 + o] = mn;
        }
      }
    }
  }
  __syncthreads();
  if(tid < 128) atomicAdd(&gstats2[tid], ssum[tid]);
  else          atomicAdd(&gstats2[tid], ssq[tid - 128]);
}

// ---------------------------------------------------------------------------
// 6) Final: BN2+ReLU on max/min endpoints. Unchanged.
// ---------------------------------------------------------------------------
__global__ __launch_bounds__(256) void final_kernel(const float* __restrict__ maxk,
                                                    const float* __restrict__ mink,
                                                    const float* __restrict__ gstats2,
                                                    const float* __restrict__ g,
                                                    const float* __restrict__ bt,
                                                    float* __restrict__ out_np){
  const int gid = blockIdx.x * 256 + threadIdx.x;
  const int o = gid & 127;
  float mean = gstats2[o] * (1.0f / M_);
  float var  = gstats2[128 + o] * (1.0f / M_) - mean * mean;
  float inv  = 1.0f / sqrtf(var + EPS_);
  float a = g[o] * inv;
  float b = bt[o] - mean * a;
  float mx = maxk[gid], mn = mink[gid];
  out_np[gid] = fmaxf(fmaxf(a * mx + b, 0.0f), fmaxf(a * mn + b, 0.0f));
}

// ---------------------------------------------------------------------------
extern "C" void kernel_launch(void* const* d_in, const int* in_sizes, int n_in,
                              void* d_out, int out_size, void* d_ws, size_t ws_size,
                              hipStream_t stream){
  (void)in_sizes; (void)n_in; (void)out_size;
  const float* xyz = (const float*)d_in[0];
  const float* pts = (const float*)d_in[1];
  const float* w0 = (const float*)d_in[2];  const float* b0  = (const float*)d_in[3];
  const float* g0 = (const float*)d_in[4];  const float* bt0 = (const float*)d_in[5];
  const float* w1 = (const float*)d_in[6];  const float* b1  = (const float*)d_in[7];
  const float* g1 = (const float*)d_in[8];  const float* bt1 = (const float*)d_in[9];
  const float* w2 = (const float*)d_in[10]; const float* b2  = (const float*)d_in[11];
  const float* g2 = (const float*)d_in[12]; const float* bt2 = (const float*)d_in[13];

  float* out    = (float*)d_out;
  float* newxyz = out;                       // (B,S,3)
  float* newpts = out + (size_t)B_ * S_ * 3; // (B,S,128)

  const size_t off_gidx  = 0;
  const size_t off_stats = off_gidx  + (size_t)M_ * 4;
  const size_t off_maxk  = off_stats + 65536;
  const size_t off_mink  = off_maxk  + (size_t)NQ_ * 128 * 4;
  const size_t off_y1    = off_mink  + (size_t)NQ_ * 128 * 4;
  const size_t need      = off_y1    + (size_t)M_ * 64 * 2;
  if(ws_size < need) return;

  char* ws = (char*)d_ws;
  int*      gidx   = (int*)     (ws + off_gidx);
  float*    gstats = (float*)   (ws + off_stats);
  float*    maxk   = (float*)   (ws + off_maxk);
  float*    mink   = (float*)   (ws + off_mink);
  uint16_t* y1t    = (uint16_t*)(ws + off_y1);

  fps_kernel  <<<B_, 256, 0, stream>>>(xyz, newxyz);
  ballq_kernel<<<NQ_ / 4, 256, 0, stream>>>(xyz, newxyz, gidx, gstats);

  layer1_kernel      <<<M_ / 256, 256, 0, stream>>>(xyz, pts, newxyz, gidx, w0, b0, y1t, gstats);
  layer2_stats_kernel<<<M_ / 512, 256, 0, stream>>>(y1t, gstats, g0, bt0, w1, b1, gstats + 128);
  layer3_kernel      <<<M_ / 512, 256, 0, stream>>>(y1t, gstats, g0, bt0, w1, b1,
                                                    gstats + 128, g1, bt1, w2, b2,
                                                    gstats + 256, maxk, mink);
  final_kernel<<<(NQ_ * 128) / 256, 256, 0, stream>>>(maxk, mink, gstats + 256, g2, bt2, newpts);
}